// Round 4
// baseline (940.484 us; speedup 1.0000x reference)
//
#include <hip/hip_runtime.h>
#include <hip/hip_bf16.h>
#include <stdint.h>

// CrossAttention: out = softmax((x@Wq)(ctx@Wk)^T * scale) @ (ctx@Wv) @ Wo + bo
// B=16, NQ=4096, NK=77, QD=512, CD=768, H=8, DH=64, INNER=512
//
// Round 3: fused qattn kernel = (x f32 -> bf16) + Q-proj GEMM + per-head
// attention -> AO bf16.  Deletes conv_bf16, xb, Qb and the attn dispatch.
// O-proj stays the m97-structure GEMM with XCD swizzle.

typedef __attribute__((ext_vector_type(8))) short bf16x8;
typedef __attribute__((ext_vector_type(4))) float f32x4;
typedef __attribute__((ext_vector_type(4))) short short4v;
typedef __attribute__((ext_vector_type(4))) float float4v;
typedef __attribute__((ext_vector_type(2))) unsigned uint2v;
typedef __attribute__((ext_vector_type(4))) unsigned uint4v;

#define DEVINL __device__ __forceinline__

DEVINL short f2bf(float f) {
  unsigned u = __builtin_bit_cast(unsigned, f);
  unsigned r = (u + 0x7FFFu + ((u >> 16) & 1u)) >> 16;  // RNE
  return (short)(unsigned short)r;
}

// packed f32x2 -> bf16x2 (RTNE), single VALU op
DEVINL unsigned pkbf(float lo, float hi) {
  unsigned r;
  asm("v_cvt_pk_bf16_f32 %0, %1, %2" : "=v"(r) : "v"(lo), "v"(hi));
  return r;
}

#define GLDS16(gp, sp)                                                \
  __builtin_amdgcn_global_load_lds(                                   \
      (const __attribute__((address_space(1))) void*)(gp),            \
      (__attribute__((address_space(3))) void*)(sp), 16, 0, 0)

// ---------------- zero fill (float4 granules) ------------------------------
__global__ __launch_bounds__(256) void fill0(float4v* __restrict__ p, int n4) {
  int i = blockIdx.x * 256 + threadIdx.x;
  if (i < n4) p[i] = float4v{0.f, 0.f, 0.f, 0.f};
}

// ---------------- weight transpose+convert: W[K][N] f32 -> Wt[N][K] bf16 ----
__global__ __launch_bounds__(256) void wt_conv(const float* __restrict__ W,
                                               short* __restrict__ Wt,
                                               int K, int N) {
  __shared__ short Tl[64][65];
  const int kt = blockIdx.y * 64, nt = blockIdx.x * 64;
#pragma unroll
  for (int i = 0; i < 16; ++i) {
    int idx = threadIdx.x + i * 256;
    int r = idx >> 6, c = idx & 63;
    Tl[c][r] = f2bf(W[(size_t)(kt + r) * N + nt + c]);
  }
  __syncthreads();
#pragma unroll
  for (int i = 0; i < 16; ++i) {
    int idx = threadIdx.x + i * 256;
    int r = idx >> 6, c = idx & 63;
    Wt[(size_t)(nt + r) * K + kt + c] = Tl[r][c];
  }
}

// ---------------- m97-structure GEMM + XCD swizzle --------------------------
// C[M][N] = A[M][K] @ Bt[N][K]^T, bf16 in. 128x128 tile, BK=64, 4 waves.
// 1-D grid = (M/128)*(N/128), must be %8==0. OUT: 0=bf16, 2=f32+bias.
template <int OUT>
__global__ __launch_bounds__(256) void gemm_m97(const short* __restrict__ A,
                                                const short* __restrict__ Bt,
                                                void* __restrict__ Cv,
                                                const float* __restrict__ bias,
                                                int M, int N, int K) {
  __shared__ short Al[128 * 64];
  __shared__ short Bl[128 * 64];

  const int tid = threadIdx.x;
  const int lane = tid & 63, w = tid >> 6;
  const int wm = w >> 1, wn = w & 1;
  const int quad = lane >> 4, l16 = lane & 15;

  const int nwg = gridDim.x;
  const int cpx = nwg >> 3;
  const int wg = blockIdx.x;
  const int swz = (wg & 7) * cpx + (wg >> 3);
  const int nnt = N >> 7;
  const int m0 = (swz / nnt) * 128, n0 = (swz % nnt) * 128;

  const int lr = lane >> 3;
  const int lc = (lane & 7) * 8;

  f32x4 acc[4][4] = {};

  for (int k0 = 0; k0 < K; k0 += 64) {
#pragma unroll
    for (int p = 0; p < 4; ++p) {
      const int row = w * 32 + p * 8;
      GLDS16(A + (size_t)(m0 + row + lr) * K + k0 + lc, &Al[row * 64]);
      GLDS16(Bt + (size_t)(n0 + row + lr) * K + k0 + lc, &Bl[row * 64]);
    }
    __syncthreads();

#pragma unroll
    for (int ks = 0; ks < 2; ++ks) {
      bf16x8 af[4], bfr[4];
#pragma unroll
      for (int m = 0; m < 4; ++m)
        af[m] = *(bf16x8*)&Al[(wm * 64 + m * 16 + l16) * 64 + ks * 32 + quad * 8];
#pragma unroll
      for (int n = 0; n < 4; ++n)
        bfr[n] = *(bf16x8*)&Bl[(wn * 64 + n * 16 + l16) * 64 + ks * 32 + quad * 8];
#pragma unroll
      for (int m = 0; m < 4; ++m)
#pragma unroll
        for (int n = 0; n < 4; ++n)
          acc[m][n] = __builtin_amdgcn_mfma_f32_16x16x32_bf16(af[m], bfr[n],
                                                              acc[m][n], 0, 0, 0);
    }
    __syncthreads();
  }

#pragma unroll
  for (int m = 0; m < 4; ++m) {
#pragma unroll
    for (int n = 0; n < 4; ++n) {
      const int col = n0 + wn * 64 + n * 16 + l16;
      const int rowb = m0 + wm * 64 + m * 16 + quad * 4;
      const float badd = (OUT == 2) ? bias[col] : 0.0f;
#pragma unroll
      for (int r = 0; r < 4; ++r) {
        if constexpr (OUT == 0)
          ((short*)Cv)[(size_t)(rowb + r) * N + col] = f2bf(acc[m][n][r]);
        else
          ((float*)Cv)[(size_t)(rowb + r) * N + col] = acc[m][n][r] + badd;
      }
    }
  }
}

// ---------------- small GEMM (f32 A): C = A[M][K]f32 @ Bt[512][K]^T ---------
// TRANS=0: bf16 C[M][512].  TRANS=1: scatter to Vtg[((b*8+h)*64+d)*104+key].
template <int TRANS>
__global__ __launch_bounds__(256) void gemm_small(const float* __restrict__ A,
                                                  const short* __restrict__ Bt,
                                                  short* __restrict__ C,
                                                  int M, int K) {
  __shared__ short Al[32][40];
  __shared__ short Bl[128][40];

  const int tid = threadIdx.x;
  const int lane = tid & 63, wid = tid >> 6;
  const int wm = wid >> 1, wn = wid & 1;
  const int quad = lane >> 4, l16 = lane & 15;
  const int m0 = blockIdx.y * 32, n0 = blockIdx.x * 128;

  f32x4 acc[4] = {};

  for (int k0 = 0; k0 < K; k0 += 32) {
    for (int idx = tid; idx < 32 * 8; idx += 256) {
      int row = idx >> 3, kq = idx & 7;
      float4v v = {};
      if (m0 + row < M)
        v = *(const float4v*)(A + (size_t)(m0 + row) * K + k0 + kq * 4);
      short4v s = {f2bf(v[0]), f2bf(v[1]), f2bf(v[2]), f2bf(v[3])};
      *(short4v*)&Al[row][kq * 4] = s;
    }
    for (int idx = tid; idx < 512; idx += 256) {
      int row = idx >> 2, kq = idx & 3;
      *(bf16x8*)&Bl[row][kq * 8] =
          *(const bf16x8*)(Bt + (size_t)(n0 + row) * K + k0 + kq * 8);
    }
    __syncthreads();

    bf16x8 a = *(bf16x8*)&Al[wm * 16 + l16][quad * 8];
#pragma unroll
    for (int n = 0; n < 4; ++n) {
      bf16x8 b = *(bf16x8*)&Bl[wn * 64 + n * 16 + l16][quad * 8];
      acc[n] = __builtin_amdgcn_mfma_f32_16x16x32_bf16(a, b, acc[n], 0, 0, 0);
    }
    __syncthreads();
  }

#pragma unroll
  for (int n = 0; n < 4; ++n) {
    const int col = n0 + wn * 64 + n * 16 + l16;
    const int rowb = m0 + wm * 16 + quad * 4;
#pragma unroll
    for (int r = 0; r < 4; ++r) {
      const int rr = rowb + r;
      if (rr < M) {
        if constexpr (TRANS == 0) {
          C[(size_t)rr * 512 + col] = f2bf(acc[n][r]);
        } else {
          const int bb = rr / 77, key = rr - bb * 77;
          C[(size_t)((bb * 8 + (col >> 6)) * 64 + (col & 63)) * 104 + key] =
              f2bf(acc[n][r]);
        }
      }
    }
  }
}

// ---------------- fused Q-proj + attention ---------------------------------
// Block: 512 thr (8 waves), 128 q-rows x full 512 cols.
// Phase 1: Q = x(f32)@wqt^T, wave tile 64x128, acc[4][8], BK=64.
// Phase 2: per head h: Q_h -> LDS (2 owner waves), stage K_h/V_h^T,
//          each wave does 16 q-rows of attention, writes AO bf16.
__global__ __launch_bounds__(512, 2) void qattn(const float* __restrict__ x,
                                                const short* __restrict__ wqt,
                                                const short* __restrict__ Kb,
                                                const short* __restrict__ Vtg,
                                                short* __restrict__ AOb) {
  __shared__ __align__(16) char smem[98304];
  float* xs = (float*)smem;                 // [128][64] f32, 32 KB
  short* wsW = (short*)(smem + 32768);      // [512][64] bf16, 64 KB
  short* Qh = (short*)smem;                 // [128][72] bf16, 18432 B
  short* Kl = (short*)(smem + 18432);       // [80][72]  bf16, 11520 B
  short* Vt = (short*)(smem + 29952);       // [64][104] bf16, 13312 B
  short* Pw = (short*)(smem + 43264);       // [8][16][104] bf16, 26624 B

  const int tid = threadIdx.x;
  const int lane = tid & 63, w = tid >> 6;
  const int wm = w >> 2, wn = w & 3;        // phase-1 wave grid 2x4
  const int quad = lane >> 4, l16 = lane & 15;
  const int m0 = blockIdx.x * 128;
  const int b = m0 >> 12;

  f32x4 acc[4][8] = {};

  // ================= phase 1: Q projection =================
  for (int k0 = 0; k0 < 512; k0 += 64) {
    // stage x tile [128][64] f32 (32 KB-chunks, 4 per wave)
#pragma unroll
    for (int p = 0; p < 4; ++p) {
      const int cid = w * 4 + p;
      const int row = cid * 4 + (lane >> 4);
      GLDS16(x + (size_t)(m0 + row) * 512 + k0 + (lane & 15) * 4,
             xs + cid * 256);
    }
    // stage wqt tile [512][64] bf16 (64 KB-chunks, 8 per wave)
#pragma unroll
    for (int p = 0; p < 8; ++p) {
      const int cid = w * 8 + p;
      const int row = cid * 8 + (lane >> 3);
      GLDS16(wqt + (size_t)row * 512 + k0 + (lane & 7) * 8, wsW + cid * 512);
    }
    __syncthreads();

#pragma unroll
    for (int ks = 0; ks < 2; ++ks) {
      bf16x8 af[4], bfr[8];
#pragma unroll
      for (int m = 0; m < 4; ++m) {
        const float* ap = xs + (wm * 64 + m * 16 + l16) * 64 + ks * 32 + quad * 8;
        float4v a0 = *(const float4v*)ap;
        float4v a1 = *(const float4v*)(ap + 4);
        uint4v u = {pkbf(a0[0], a0[1]), pkbf(a0[2], a0[3]),
                    pkbf(a1[0], a1[1]), pkbf(a1[2], a1[3])};
        af[m] = __builtin_bit_cast(bf16x8, u);
      }
#pragma unroll
      for (int n = 0; n < 8; ++n)
        bfr[n] = *(bf16x8*)&wsW[(wn * 128 + n * 16 + l16) * 64 + ks * 32 + quad * 8];
#pragma unroll
      for (int m = 0; m < 4; ++m)
#pragma unroll
        for (int n = 0; n < 8; ++n)
          acc[m][n] = __builtin_amdgcn_mfma_f32_16x16x32_bf16(af[m], bfr[n],
                                                              acc[m][n], 0, 0, 0);
    }
    __syncthreads();
  }

  // ================= phase 2: per-head attention =================
  for (int h = 0; h < 8; ++h) {
    if (h) __syncthreads();  // protect LDS from previous round's readers

    // (a) owner waves dump Q_h [128][64] -> Qh (C-layout: row quad*4+r, col l16)
    if (wn == (h >> 1)) {
      const int nb = (h & 1) * 4;
#pragma unroll
      for (int m = 0; m < 4; ++m)
#pragma unroll
        for (int n = 0; n < 4; ++n)
#pragma unroll
          for (int r = 0; r < 4; ++r)
            Qh[(wm * 64 + m * 16 + quad * 4 + r) * 72 + n * 16 + l16] =
                f2bf(acc[m][nb + n][r]);
    }
    // (b) stage K_h rows 0..76 (rows 77..79 garbage, masked later)
    for (int idx = tid; idx < 616; idx += 512) {
      const int r = idx >> 3, c = idx & 7;
      *(bf16x8*)&Kl[r * 72 + c * 8] =
          *(const bf16x8*)(Kb + ((size_t)b * 77 + r) * 512 + h * 64 + c * 8);
    }
    // (c) stage V_h^T [64][104] linearly (13 KB-chunks)
    for (int cid = w; cid < 13; cid += 8)
      GLDS16(Vtg + (size_t)(b * 8 + h) * 6656 + cid * 512 + lane * 8,
             Vt + cid * 512);
    __syncthreads();

    // (d) attention for this wave's 16 q rows
    bf16x8 qfr[2];
#pragma unroll
    for (int ks = 0; ks < 2; ++ks)
      qfr[ks] = *(bf16x8*)&Qh[(w * 16 + l16) * 72 + ks * 32 + quad * 8];

    f32x4 c[5] = {};
#pragma unroll
    for (int f = 0; f < 5; ++f)
#pragma unroll
      for (int ks = 0; ks < 2; ++ks) {
        bf16x8 a = *(bf16x8*)&Kl[(f * 16 + l16) * 72 + ks * 32 + quad * 8];
        c[f] = __builtin_amdgcn_mfma_f32_16x16x32_bf16(a, qfr[ks], c[f], 0, 0, 0);
      }

    float mx = -1e30f;
#pragma unroll
    for (int f = 0; f < 5; ++f)
#pragma unroll
      for (int r = 0; r < 4; ++r) {
        const int key = f * 16 + quad * 4 + r;
        float v = c[f][r] * 0.125f;
        v = (key < 77) ? v : -1e30f;
        c[f][r] = v;
        mx = fmaxf(mx, v);
      }
    mx = fmaxf(mx, __shfl_xor(mx, 16));
    mx = fmaxf(mx, __shfl_xor(mx, 32));

    short* pbase = Pw + (w * 16 + l16) * 104;
    *(uint2v*)(pbase + 80 + quad * 4) = uint2v{0u, 0u};  // zero pad keys 80..95
    float sum = 0.f;
#pragma unroll
    for (int f = 0; f < 5; ++f) {
      float e0 = __expf(c[f][0] - mx), e1 = __expf(c[f][1] - mx);
      float e2 = __expf(c[f][2] - mx), e3 = __expf(c[f][3] - mx);
      sum += (e0 + e1) + (e2 + e3);
      uint2v s = {pkbf(e0, e1), pkbf(e2, e3)};
      *(uint2v*)(pbase + f * 16 + quad * 4) = s;
    }
    sum += __shfl_xor(sum, 16);
    sum += __shfl_xor(sum, 32);
    const float inv = 1.0f / sum;

    bf16x8 pb[3];
#pragma unroll
    for (int ks = 0; ks < 3; ++ks)
      pb[ks] = *(bf16x8*)(pbase + ks * 32 + quad * 8);

    f32x4 o[4] = {};
#pragma unroll
    for (int mt = 0; mt < 4; ++mt)
#pragma unroll
      for (int ks = 0; ks < 3; ++ks) {
        bf16x8 a = *(bf16x8*)&Vt[(mt * 16 + l16) * 104 + ks * 32 + quad * 8];
        o[mt] = __builtin_amdgcn_mfma_f32_16x16x32_bf16(a, pb[ks], o[mt], 0, 0, 0);
      }

    short* op = AOb + ((size_t)m0 + w * 16 + l16) * 512 + h * 64;
#pragma unroll
    for (int mt = 0; mt < 4; ++mt) {
      uint2v s = {pkbf(o[mt][0] * inv, o[mt][1] * inv),
                  pkbf(o[mt][2] * inv, o[mt][3] * inv)};
      *(uint2v*)(op + mt * 16 + quad * 4) = s;
    }
  }
}

extern "C" void kernel_launch(void* const* d_in, const int* in_sizes, int n_in,
                              void* d_out, int out_size, void* d_ws, size_t ws_size,
                              hipStream_t stream) {
  const float* x   = (const float*)d_in[0];
  const float* ctx = (const float*)d_in[1];
  const float* Wq  = (const float*)d_in[2];
  const float* Wk  = (const float*)d_in[3];
  const float* Wv  = (const float*)d_in[4];
  const float* Wo  = (const float*)d_in[5];
  const float* bo  = (const float*)d_in[6];
  float* out = (float*)d_out;

  char* ws = (char*)d_ws;
  size_t off = 0;
  short* wqt = (short*)(ws + off); off += 512 * 512 * 2;
  short* wkt = (short*)(ws + off); off += 768 * 512 * 2;
  short* wvt = (short*)(ws + off); off += 768 * 512 * 2;
  short* wot = (short*)(ws + off); off += 512 * 512 * 2;
  short* Kb  = (short*)(ws + off); off += 1232 * 512 * 2;
  short* Vtg = (short*)(ws + off); off += (size_t)16 * 8 * 64 * 104 * 2;
  short* AOb = (short*)(ws + off); off += (size_t)65536 * 512 * 2;

  // weights -> bf16 transposed [N][K]
  wt_conv<<<dim3(8, 8), 256, 0, stream>>>(Wq, wqt, 512, 512);
  wt_conv<<<dim3(8, 12), 256, 0, stream>>>(Wk, wkt, 768, 512);
  wt_conv<<<dim3(8, 12), 256, 0, stream>>>(Wv, wvt, 768, 512);
  wt_conv<<<dim3(8, 8), 256, 0, stream>>>(Wo, wot, 512, 512);

  // zero-fill Vtg (pads must be 0), then K/V projections from f32 ctx
  fill0<<<416, 256, 0, stream>>>((float4v*)Vtg, 106496);
  gemm_small<0><<<dim3(4, 39), 256, 0, stream>>>(ctx, wkt, Kb, 1232, 768);
  gemm_small<1><<<dim3(4, 39), 256, 0, stream>>>(ctx, wvt, Vtg, 1232, 768);

  // fused Q-proj + attention -> AOb bf16
  qattn<<<512, 512, 0, stream>>>(x, wqt, Kb, Vtg, AOb);

  // output projection + bias -> f32 d_out
  gemm_m97<2><<<2048, 256, 0, stream>>>(AOb, wot, out, bo, 65536, 512, 512);
}

// Round 5
// 260.215 us; speedup vs baseline: 3.6143x; 3.6143x over previous
//
#include <hip/hip_runtime.h>
#include <hip/hip_bf16.h>
#include <stdint.h>

// CrossAttention: out = softmax((x@Wq)(ctx@Wk)^T * scale) @ (ctx@Wv) @ Wo + bo
// B=16, NQ=4096, NK=77, QD=512, CD=768, H=8, DH=64, INNER=512
//
// Round 4 fix: round-3's fused qattn spilled acc[4][8] to scratch because
// phase 2 indexed it with runtime (h&1) (rule #20). Full-unroll the head
// loop so every acc index is compile-time. No other structural change.

typedef __attribute__((ext_vector_type(8))) short bf16x8;
typedef __attribute__((ext_vector_type(4))) float f32x4;
typedef __attribute__((ext_vector_type(4))) short short4v;
typedef __attribute__((ext_vector_type(4))) float float4v;
typedef __attribute__((ext_vector_type(2))) unsigned uint2v;
typedef __attribute__((ext_vector_type(4))) unsigned uint4v;

#define DEVINL __device__ __forceinline__

DEVINL short f2bf(float f) {
  unsigned u = __builtin_bit_cast(unsigned, f);
  unsigned r = (u + 0x7FFFu + ((u >> 16) & 1u)) >> 16;  // RNE
  return (short)(unsigned short)r;
}

// packed f32x2 -> bf16x2 (RTNE), single VALU op
DEVINL unsigned pkbf(float lo, float hi) {
  unsigned r;
  asm("v_cvt_pk_bf16_f32 %0, %1, %2" : "=v"(r) : "v"(lo), "v"(hi));
  return r;
}

#define GLDS16(gp, sp)                                                \
  __builtin_amdgcn_global_load_lds(                                   \
      (const __attribute__((address_space(1))) void*)(gp),            \
      (__attribute__((address_space(3))) void*)(sp), 16, 0, 0)

// ---------------- zero fill (float4 granules) ------------------------------
__global__ __launch_bounds__(256) void fill0(float4v* __restrict__ p, int n4) {
  int i = blockIdx.x * 256 + threadIdx.x;
  if (i < n4) p[i] = float4v{0.f, 0.f, 0.f, 0.f};
}

// ---------------- weight transpose+convert: W[K][N] f32 -> Wt[N][K] bf16 ----
__global__ __launch_bounds__(256) void wt_conv(const float* __restrict__ W,
                                               short* __restrict__ Wt,
                                               int K, int N) {
  __shared__ short Tl[64][65];
  const int kt = blockIdx.y * 64, nt = blockIdx.x * 64;
#pragma unroll
  for (int i = 0; i < 16; ++i) {
    int idx = threadIdx.x + i * 256;
    int r = idx >> 6, c = idx & 63;
    Tl[c][r] = f2bf(W[(size_t)(kt + r) * N + nt + c]);
  }
  __syncthreads();
#pragma unroll
  for (int i = 0; i < 16; ++i) {
    int idx = threadIdx.x + i * 256;
    int r = idx >> 6, c = idx & 63;
    Wt[(size_t)(nt + r) * K + kt + c] = Tl[r][c];
  }
}

// ---------------- m97-structure GEMM + XCD swizzle --------------------------
// C[M][N] = A[M][K] @ Bt[N][K]^T, bf16 in. 128x128 tile, BK=64, 4 waves.
// 1-D grid = (M/128)*(N/128), must be %8==0. OUT: 0=bf16, 2=f32+bias.
template <int OUT>
__global__ __launch_bounds__(256) void gemm_m97(const short* __restrict__ A,
                                                const short* __restrict__ Bt,
                                                void* __restrict__ Cv,
                                                const float* __restrict__ bias,
                                                int M, int N, int K) {
  __shared__ short Al[128 * 64];
  __shared__ short Bl[128 * 64];

  const int tid = threadIdx.x;
  const int lane = tid & 63, w = tid >> 6;
  const int wm = w >> 1, wn = w & 1;
  const int quad = lane >> 4, l16 = lane & 15;

  const int nwg = gridDim.x;
  const int cpx = nwg >> 3;
  const int wg = blockIdx.x;
  const int swz = (wg & 7) * cpx + (wg >> 3);
  const int nnt = N >> 7;
  const int m0 = (swz / nnt) * 128, n0 = (swz % nnt) * 128;

  const int lr = lane >> 3;
  const int lc = (lane & 7) * 8;

  f32x4 acc[4][4] = {};

  for (int k0 = 0; k0 < K; k0 += 64) {
#pragma unroll
    for (int p = 0; p < 4; ++p) {
      const int row = w * 32 + p * 8;
      GLDS16(A + (size_t)(m0 + row + lr) * K + k0 + lc, &Al[row * 64]);
      GLDS16(Bt + (size_t)(n0 + row + lr) * K + k0 + lc, &Bl[row * 64]);
    }
    __syncthreads();

#pragma unroll
    for (int ks = 0; ks < 2; ++ks) {
      bf16x8 af[4], bfr[4];
#pragma unroll
      for (int m = 0; m < 4; ++m)
        af[m] = *(bf16x8*)&Al[(wm * 64 + m * 16 + l16) * 64 + ks * 32 + quad * 8];
#pragma unroll
      for (int n = 0; n < 4; ++n)
        bfr[n] = *(bf16x8*)&Bl[(wn * 64 + n * 16 + l16) * 64 + ks * 32 + quad * 8];
#pragma unroll
      for (int m = 0; m < 4; ++m)
#pragma unroll
        for (int n = 0; n < 4; ++n)
          acc[m][n] = __builtin_amdgcn_mfma_f32_16x16x32_bf16(af[m], bfr[n],
                                                              acc[m][n], 0, 0, 0);
    }
    __syncthreads();
  }

#pragma unroll
  for (int m = 0; m < 4; ++m) {
#pragma unroll
    for (int n = 0; n < 4; ++n) {
      const int col = n0 + wn * 64 + n * 16 + l16;
      const int rowb = m0 + wm * 64 + m * 16 + quad * 4;
      const float badd = (OUT == 2) ? bias[col] : 0.0f;
#pragma unroll
      for (int r = 0; r < 4; ++r) {
        if constexpr (OUT == 0)
          ((short*)Cv)[(size_t)(rowb + r) * N + col] = f2bf(acc[m][n][r]);
        else
          ((float*)Cv)[(size_t)(rowb + r) * N + col] = acc[m][n][r] + badd;
      }
    }
  }
}

// ---------------- small GEMM (f32 A): C = A[M][K]f32 @ Bt[512][K]^T ---------
// TRANS=0: bf16 C[M][512].  TRANS=1: scatter to Vtg[((b*8+h)*64+d)*104+key].
template <int TRANS>
__global__ __launch_bounds__(256) void gemm_small(const float* __restrict__ A,
                                                  const short* __restrict__ Bt,
                                                  short* __restrict__ C,
                                                  int M, int K) {
  __shared__ short Al[32][40];
  __shared__ short Bl[128][40];

  const int tid = threadIdx.x;
  const int lane = tid & 63, wid = tid >> 6;
  const int wm = wid >> 1, wn = wid & 1;
  const int quad = lane >> 4, l16 = lane & 15;
  const int m0 = blockIdx.y * 32, n0 = blockIdx.x * 128;

  f32x4 acc[4] = {};

  for (int k0 = 0; k0 < K; k0 += 32) {
    for (int idx = tid; idx < 32 * 8; idx += 256) {
      int row = idx >> 3, kq = idx & 7;
      float4v v = {};
      if (m0 + row < M)
        v = *(const float4v*)(A + (size_t)(m0 + row) * K + k0 + kq * 4);
      short4v s = {f2bf(v[0]), f2bf(v[1]), f2bf(v[2]), f2bf(v[3])};
      *(short4v*)&Al[row][kq * 4] = s;
    }
    for (int idx = tid; idx < 512; idx += 256) {
      int row = idx >> 2, kq = idx & 3;
      *(bf16x8*)&Bl[row][kq * 8] =
          *(const bf16x8*)(Bt + (size_t)(n0 + row) * K + k0 + kq * 8);
    }
    __syncthreads();

    bf16x8 a = *(bf16x8*)&Al[wm * 16 + l16][quad * 8];
#pragma unroll
    for (int n = 0; n < 4; ++n) {
      bf16x8 b = *(bf16x8*)&Bl[wn * 64 + n * 16 + l16][quad * 8];
      acc[n] = __builtin_amdgcn_mfma_f32_16x16x32_bf16(a, b, acc[n], 0, 0, 0);
    }
    __syncthreads();
  }

#pragma unroll
  for (int n = 0; n < 4; ++n) {
    const int col = n0 + wn * 64 + n * 16 + l16;
    const int rowb = m0 + wm * 16 + quad * 4;
#pragma unroll
    for (int r = 0; r < 4; ++r) {
      const int rr = rowb + r;
      if (rr < M) {
        if constexpr (TRANS == 0) {
          C[(size_t)rr * 512 + col] = f2bf(acc[n][r]);
        } else {
          const int bb = rr / 77, key = rr - bb * 77;
          C[(size_t)((bb * 8 + (col >> 6)) * 64 + (col & 63)) * 104 + key] =
              f2bf(acc[n][r]);
        }
      }
    }
  }
}

// ---------------- fused Q-proj + attention ---------------------------------
// Block: 512 thr (8 waves), 128 q-rows x full 512 cols.
// Phase 1: Q = x(f32)@wqt^T, wave tile 64x128, acc[4][8], BK=64.
// Phase 2: FULLY UNROLLED per head h (static acc indexing — rule #20):
//          owner waves dump Q_h -> LDS, stage K_h/V_h^T, each wave does
//          16 q-rows of attention, writes AO bf16.
__global__ __launch_bounds__(512, 2) void qattn(const float* __restrict__ x,
                                                const short* __restrict__ wqt,
                                                const short* __restrict__ Kb,
                                                const short* __restrict__ Vtg,
                                                short* __restrict__ AOb) {
  __shared__ __align__(16) char smem[98304];
  float* xs = (float*)smem;                 // [128][64] f32, 32 KB
  short* wsW = (short*)(smem + 32768);      // [512][64] bf16, 64 KB
  short* Qh = (short*)smem;                 // [128][72] bf16, 18432 B
  short* Kl = (short*)(smem + 18432);       // [80][72]  bf16, 11520 B
  short* Vt = (short*)(smem + 29952);       // [64][104] bf16, 13312 B
  short* Pw = (short*)(smem + 43264);       // [8][16][104] bf16, 26624 B

  const int tid = threadIdx.x;
  const int lane = tid & 63, w = tid >> 6;
  const int wm = w >> 2, wn = w & 3;        // phase-1 wave grid 2x4
  const int quad = lane >> 4, l16 = lane & 15;
  const int m0 = blockIdx.x * 128;
  const int b = m0 >> 12;

  f32x4 acc[4][8] = {};

  // ================= phase 1: Q projection =================
  for (int k0 = 0; k0 < 512; k0 += 64) {
#pragma unroll
    for (int p = 0; p < 4; ++p) {
      const int cid = w * 4 + p;
      const int row = cid * 4 + (lane >> 4);
      GLDS16(x + (size_t)(m0 + row) * 512 + k0 + (lane & 15) * 4,
             xs + cid * 256);
    }
#pragma unroll
    for (int p = 0; p < 8; ++p) {
      const int cid = w * 8 + p;
      const int row = cid * 8 + (lane >> 3);
      GLDS16(wqt + (size_t)row * 512 + k0 + (lane & 7) * 8, wsW + cid * 512);
    }
    __syncthreads();

#pragma unroll
    for (int ks = 0; ks < 2; ++ks) {
      bf16x8 af[4], bfr[8];
#pragma unroll
      for (int m = 0; m < 4; ++m) {
        const float* ap = xs + (wm * 64 + m * 16 + l16) * 64 + ks * 32 + quad * 8;
        float4v a0 = *(const float4v*)ap;
        float4v a1 = *(const float4v*)(ap + 4);
        uint4v u = {pkbf(a0[0], a0[1]), pkbf(a0[2], a0[3]),
                    pkbf(a1[0], a1[1]), pkbf(a1[2], a1[3])};
        af[m] = __builtin_bit_cast(bf16x8, u);
      }
#pragma unroll
      for (int n = 0; n < 8; ++n)
        bfr[n] = *(bf16x8*)&wsW[(wn * 128 + n * 16 + l16) * 64 + ks * 32 + quad * 8];
#pragma unroll
      for (int m = 0; m < 4; ++m)
#pragma unroll
        for (int n = 0; n < 8; ++n)
          acc[m][n] = __builtin_amdgcn_mfma_f32_16x16x32_bf16(af[m], bfr[n],
                                                              acc[m][n], 0, 0, 0);
    }
    __syncthreads();
  }

  // ================= phase 2: per-head attention (FULL UNROLL) =============
#pragma unroll
  for (int h = 0; h < 8; ++h) {
    if (h) __syncthreads();

    // (a) owner waves dump Q_h [128][64] -> Qh; h is compile-time here, so
    // acc[m][(h&1)*4 + n] is a static index (stays in registers).
    if (wn == (h >> 1)) {
#pragma unroll
      for (int m = 0; m < 4; ++m)
#pragma unroll
        for (int n = 0; n < 4; ++n)
#pragma unroll
          for (int r = 0; r < 4; ++r)
            Qh[(wm * 64 + m * 16 + quad * 4 + r) * 72 + n * 16 + l16] =
                f2bf(acc[m][(h & 1) * 4 + n][r]);
    }
    // (b) stage K_h rows 0..76 (rows 77..79 garbage, masked later)
    for (int idx = tid; idx < 616; idx += 512) {
      const int r = idx >> 3, c = idx & 7;
      *(bf16x8*)&Kl[r * 72 + c * 8] =
          *(const bf16x8*)(Kb + ((size_t)b * 77 + r) * 512 + h * 64 + c * 8);
    }
    // (c) stage V_h^T [64][104] linearly (13 KB-chunks)
    for (int cid = w; cid < 13; cid += 8)
      GLDS16(Vtg + (size_t)(b * 8 + h) * 6656 + cid * 512 + lane * 8,
             Vt + cid * 512);
    __syncthreads();

    // (d) attention for this wave's 16 q rows
    bf16x8 qfr[2];
#pragma unroll
    for (int ks = 0; ks < 2; ++ks)
      qfr[ks] = *(bf16x8*)&Qh[(w * 16 + l16) * 72 + ks * 32 + quad * 8];

    f32x4 c[5] = {};
#pragma unroll
    for (int f = 0; f < 5; ++f)
#pragma unroll
      for (int ks = 0; ks < 2; ++ks) {
        bf16x8 a = *(bf16x8*)&Kl[(f * 16 + l16) * 72 + ks * 32 + quad * 8];
        c[f] = __builtin_amdgcn_mfma_f32_16x16x32_bf16(a, qfr[ks], c[f], 0, 0, 0);
      }

    float mx = -1e30f;
#pragma unroll
    for (int f = 0; f < 5; ++f)
#pragma unroll
      for (int r = 0; r < 4; ++r) {
        const int key = f * 16 + quad * 4 + r;
        float v = c[f][r] * 0.125f;
        v = (key < 77) ? v : -1e30f;
        c[f][r] = v;
        mx = fmaxf(mx, v);
      }
    mx = fmaxf(mx, __shfl_xor(mx, 16));
    mx = fmaxf(mx, __shfl_xor(mx, 32));

    short* pbase = Pw + (w * 16 + l16) * 104;
    *(uint2v*)(pbase + 80 + quad * 4) = uint2v{0u, 0u};  // zero pad keys 80..95
    float sum = 0.f;
#pragma unroll
    for (int f = 0; f < 5; ++f) {
      float e0 = __expf(c[f][0] - mx), e1 = __expf(c[f][1] - mx);
      float e2 = __expf(c[f][2] - mx), e3 = __expf(c[f][3] - mx);
      sum += (e0 + e1) + (e2 + e3);
      uint2v s = {pkbf(e0, e1), pkbf(e2, e3)};
      *(uint2v*)(pbase + f * 16 + quad * 4) = s;
    }
    sum += __shfl_xor(sum, 16);
    sum += __shfl_xor(sum, 32);
    const float inv = 1.0f / sum;

    bf16x8 pb[3];
#pragma unroll
    for (int ks = 0; ks < 3; ++ks)
      pb[ks] = *(bf16x8*)(pbase + ks * 32 + quad * 8);

    f32x4 o[4] = {};
#pragma unroll
    for (int mt = 0; mt < 4; ++mt)
#pragma unroll
      for (int ks = 0; ks < 3; ++ks) {
        bf16x8 a = *(bf16x8*)&Vt[(mt * 16 + l16) * 104 + ks * 32 + quad * 8];
        o[mt] = __builtin_amdgcn_mfma_f32_16x16x32_bf16(a, pb[ks], o[mt], 0, 0, 0);
      }

    short* op = AOb + ((size_t)m0 + w * 16 + l16) * 512 + h * 64;
#pragma unroll
    for (int mt = 0; mt < 4; ++mt) {
      uint2v s = {pkbf(o[mt][0] * inv, o[mt][1] * inv),
                  pkbf(o[mt][2] * inv, o[mt][3] * inv)};
      *(uint2v*)(op + mt * 16 + quad * 4) = s;
    }
  }
}

extern "C" void kernel_launch(void* const* d_in, const int* in_sizes, int n_in,
                              void* d_out, int out_size, void* d_ws, size_t ws_size,
                              hipStream_t stream) {
  const float* x   = (const float*)d_in[0];
  const float* ctx = (const float*)d_in[1];
  const float* Wq  = (const float*)d_in[2];
  const float* Wk  = (const float*)d_in[3];
  const float* Wv  = (const float*)d_in[4];
  const float* Wo  = (const float*)d_in[5];
  const float* bo  = (const float*)d_in[6];
  float* out = (float*)d_out;

  char* ws = (char*)d_ws;
  size_t off = 0;
  short* wqt = (short*)(ws + off); off += 512 * 512 * 2;
  short* wkt = (short*)(ws + off); off += 768 * 512 * 2;
  short* wvt = (short*)(ws + off); off += 768 * 512 * 2;
  short* wot = (short*)(ws + off); off += 512 * 512 * 2;
  short* Kb  = (short*)(ws + off); off += 1232 * 512 * 2;
  short* Vtg = (short*)(ws + off); off += (size_t)16 * 8 * 64 * 104 * 2;
  short* AOb = (short*)(ws + off); off += (size_t)65536 * 512 * 2;

  // weights -> bf16 transposed [N][K]
  wt_conv<<<dim3(8, 8), 256, 0, stream>>>(Wq, wqt, 512, 512);
  wt_conv<<<dim3(8, 12), 256, 0, stream>>>(Wk, wkt, 768, 512);
  wt_conv<<<dim3(8, 12), 256, 0, stream>>>(Wv, wvt, 768, 512);
  wt_conv<<<dim3(8, 8), 256, 0, stream>>>(Wo, wot, 512, 512);

  // zero-fill Vtg (pads must be 0), then K/V projections from f32 ctx
  fill0<<<416, 256, 0, stream>>>((float4v*)Vtg, 106496);
  gemm_small<0><<<dim3(4, 39), 256, 0, stream>>>(ctx, wkt, Kb, 1232, 768);
  gemm_small<1><<<dim3(4, 39), 256, 0, stream>>>(ctx, wvt, Vtg, 1232, 768);

  // fused Q-proj + attention -> AOb bf16
  qattn<<<512, 512, 0, stream>>>(x, wqt, Kb, Vtg, AOb);

  // output projection + bias -> f32 d_out
  gemm_m97<2><<<2048, 256, 0, stream>>>(AOb, wot, out, bo, 65536, 512, 512);
}

// Round 7
// 230.410 us; speedup vs baseline: 4.0818x; 1.1294x over previous
//
#include <hip/hip_runtime.h>
#include <hip/hip_bf16.h>
#include <stdint.h>

// CrossAttention: out = softmax((x@Wq)(ctx@Wk)^T * scale) @ (ctx@Wv) @ Wo + bo
// B=16, NQ=4096, NK=77, QD=512, CD=768, H=8, DH=64, INNER=512
//
// Round 7: qattn = 16 waves (1024 thr, 4 waves/SIMD), NO swizzles.
// Phase 1: reg-staged PADDED LDS tiles (xb [128][72] bf16 converted once,
// wsW [512][72]) — pad kills the 16-way conflicts. Phase 2: 2 heads/iter,
// round-5-proven math, padded strides, P-pad handled in-register.

typedef __attribute__((ext_vector_type(8))) short bf16x8;
typedef __attribute__((ext_vector_type(4))) float f32x4;
typedef __attribute__((ext_vector_type(4))) short short4v;
typedef __attribute__((ext_vector_type(4))) float float4v;
typedef __attribute__((ext_vector_type(2))) unsigned uint2v;
typedef __attribute__((ext_vector_type(4))) unsigned uint4v;

#define DEVINL __device__ __forceinline__

DEVINL short f2bf(float f) {
  unsigned u = __builtin_bit_cast(unsigned, f);
  unsigned r = (u + 0x7FFFu + ((u >> 16) & 1u)) >> 16;  // RNE
  return (short)(unsigned short)r;
}

// packed f32x2 -> bf16x2 (RTNE), single VALU op
DEVINL unsigned pkbf(float lo, float hi) {
  unsigned r;
  asm("v_cvt_pk_bf16_f32 %0, %1, %2" : "=v"(r) : "v"(lo), "v"(hi));
  return r;
}

#define GLDS16(gp, sp)                                                \
  __builtin_amdgcn_global_load_lds(                                   \
      (const __attribute__((address_space(1))) void*)(gp),            \
      (__attribute__((address_space(3))) void*)(sp), 16, 0, 0)

// ---------------- zero fill (float4 granules) ------------------------------
__global__ __launch_bounds__(256) void fill0(float4v* __restrict__ p, int n4) {
  int i = blockIdx.x * 256 + threadIdx.x;
  if (i < n4) p[i] = float4v{0.f, 0.f, 0.f, 0.f};
}

// ---------------- weight transpose+convert: W[K][N] f32 -> Wt[N][K] bf16 ----
__global__ __launch_bounds__(256) void wt_conv(const float* __restrict__ W,
                                               short* __restrict__ Wt,
                                               int K, int N) {
  __shared__ short Tl[64][65];
  const int kt = blockIdx.y * 64, nt = blockIdx.x * 64;
#pragma unroll
  for (int i = 0; i < 16; ++i) {
    int idx = threadIdx.x + i * 256;
    int r = idx >> 6, c = idx & 63;
    Tl[c][r] = f2bf(W[(size_t)(kt + r) * N + nt + c]);
  }
  __syncthreads();
#pragma unroll
  for (int i = 0; i < 16; ++i) {
    int idx = threadIdx.x + i * 256;
    int r = idx >> 6, c = idx & 63;
    Wt[(size_t)(nt + r) * K + kt + c] = Tl[r][c];
  }
}

// ---------------- m97-structure GEMM + XCD swizzle --------------------------
// C[M][N] = A[M][K] @ Bt[N][K]^T, bf16 in. 128x128 tile, BK=64, 4 waves.
// 1-D grid = (M/128)*(N/128), must be %8==0. OUT: 0=bf16, 2=f32+bias.
template <int OUT>
__global__ __launch_bounds__(256) void gemm_m97(const short* __restrict__ A,
                                                const short* __restrict__ Bt,
                                                void* __restrict__ Cv,
                                                const float* __restrict__ bias,
                                                int M, int N, int K) {
  __shared__ short Al[128 * 64];
  __shared__ short Bl[128 * 64];

  const int tid = threadIdx.x;
  const int lane = tid & 63, w = tid >> 6;
  const int wm = w >> 1, wn = w & 1;
  const int quad = lane >> 4, l16 = lane & 15;

  const int nwg = gridDim.x;
  const int cpx = nwg >> 3;
  const int wg = blockIdx.x;
  const int swz = (wg & 7) * cpx + (wg >> 3);
  const int nnt = N >> 7;
  const int m0 = (swz / nnt) * 128, n0 = (swz % nnt) * 128;

  const int lr = lane >> 3;
  const int lc = (lane & 7) * 8;

  f32x4 acc[4][4] = {};

  for (int k0 = 0; k0 < K; k0 += 64) {
#pragma unroll
    for (int p = 0; p < 4; ++p) {
      const int row = w * 32 + p * 8;
      GLDS16(A + (size_t)(m0 + row + lr) * K + k0 + lc, &Al[row * 64]);
      GLDS16(Bt + (size_t)(n0 + row + lr) * K + k0 + lc, &Bl[row * 64]);
    }
    __syncthreads();

#pragma unroll
    for (int ks = 0; ks < 2; ++ks) {
      bf16x8 af[4], bfr[4];
#pragma unroll
      for (int m = 0; m < 4; ++m)
        af[m] = *(bf16x8*)&Al[(wm * 64 + m * 16 + l16) * 64 + ks * 32 + quad * 8];
#pragma unroll
      for (int n = 0; n < 4; ++n)
        bfr[n] = *(bf16x8*)&Bl[(wn * 64 + n * 16 + l16) * 64 + ks * 32 + quad * 8];
#pragma unroll
      for (int m = 0; m < 4; ++m)
#pragma unroll
        for (int n = 0; n < 4; ++n)
          acc[m][n] = __builtin_amdgcn_mfma_f32_16x16x32_bf16(af[m], bfr[n],
                                                              acc[m][n], 0, 0, 0);
    }
    __syncthreads();
  }

#pragma unroll
  for (int m = 0; m < 4; ++m) {
#pragma unroll
    for (int n = 0; n < 4; ++n) {
      const int col = n0 + wn * 64 + n * 16 + l16;
      const int rowb = m0 + wm * 64 + m * 16 + quad * 4;
      const float badd = (OUT == 2) ? bias[col] : 0.0f;
#pragma unroll
      for (int r = 0; r < 4; ++r) {
        if constexpr (OUT == 0)
          ((short*)Cv)[(size_t)(rowb + r) * N + col] = f2bf(acc[m][n][r]);
        else
          ((float*)Cv)[(size_t)(rowb + r) * N + col] = acc[m][n][r] + badd;
      }
    }
  }
}

// ---------------- small GEMM (f32 A): C = A[M][K]f32 @ Bt[512][K]^T ---------
// TRANS=0: bf16 C[M][512].  TRANS=1: scatter to Vtg[((b*8+h)*64+d)*96+key].
template <int TRANS>
__global__ __launch_bounds__(256) void gemm_small(const float* __restrict__ A,
                                                  const short* __restrict__ Bt,
                                                  short* __restrict__ C,
                                                  int M, int K) {
  __shared__ short Al[32][40];
  __shared__ short Bl[128][40];

  const int tid = threadIdx.x;
  const int lane = tid & 63, wid = tid >> 6;
  const int wm = wid >> 1, wn = wid & 1;
  const int quad = lane >> 4, l16 = lane & 15;
  const int m0 = blockIdx.y * 32, n0 = blockIdx.x * 128;

  f32x4 acc[4] = {};

  for (int k0 = 0; k0 < K; k0 += 32) {
    for (int idx = tid; idx < 32 * 8; idx += 256) {
      int row = idx >> 3, kq = idx & 7;
      float4v v = {};
      if (m0 + row < M)
        v = *(const float4v*)(A + (size_t)(m0 + row) * K + k0 + kq * 4);
      short4v s = {f2bf(v[0]), f2bf(v[1]), f2bf(v[2]), f2bf(v[3])};
      *(short4v*)&Al[row][kq * 4] = s;
    }
    for (int idx = tid; idx < 512; idx += 256) {
      int row = idx >> 2, kq = idx & 3;
      *(bf16x8*)&Bl[row][kq * 8] =
          *(const bf16x8*)(Bt + (size_t)(n0 + row) * K + k0 + kq * 8);
    }
    __syncthreads();

    bf16x8 a = *(bf16x8*)&Al[wm * 16 + l16][quad * 8];
#pragma unroll
    for (int n = 0; n < 4; ++n) {
      bf16x8 b = *(bf16x8*)&Bl[wn * 64 + n * 16 + l16][quad * 8];
      acc[n] = __builtin_amdgcn_mfma_f32_16x16x32_bf16(a, b, acc[n], 0, 0, 0);
    }
    __syncthreads();
  }

#pragma unroll
  for (int n = 0; n < 4; ++n) {
    const int col = n0 + wn * 64 + n * 16 + l16;
    const int rowb = m0 + wm * 16 + quad * 4;
#pragma unroll
    for (int r = 0; r < 4; ++r) {
      const int rr = rowb + r;
      if (rr < M) {
        if constexpr (TRANS == 0) {
          C[(size_t)rr * 512 + col] = f2bf(acc[n][r]);
        } else {
          const int bb = rr / 77, key = rr - bb * 77;
          C[(size_t)((bb * 8 + (col >> 6)) * 64 + (col & 63)) * 96 + key] =
              f2bf(acc[n][r]);
        }
      }
    }
  }
}

// ---------------- fused Q-proj + attention ---------------------------------
// 1024 thr (16 waves). Phase 1: wave grid 2x8 (wm=w>>3 row-half, wn=w&7
// head/col), wave tile 64x64, acc[4][4]; xb/wsW reg-staged, padded stride 72.
// Phase 2: 4 iters x 2 heads; wave computes head it*2+wm for rows wn*16..+15.
__global__ __launch_bounds__(1024) void qattn(const float* __restrict__ x,
                                              const short* __restrict__ wqt,
                                              const short* __restrict__ Kb,
                                              const short* __restrict__ Vtg,
                                              short* __restrict__ AOb) {
  __shared__ __align__(16) char smem[125440];
  short* xb  = (short*)smem;               // ph1: [128][72] bf16, 18432 B
  short* wsW = (short*)(smem + 18432);     // ph1: [512][72] bf16, 73728 B
  short* Qh  = (short*)smem;               // ph2: [2][128][72], 36864 B
  short* Kl  = (short*)(smem + 36864);     // ph2: [2][80][72], 23040 B
  short* Vt  = (short*)(smem + 59904);     // ph2: [2][64][96], 24576 B
  short* Pw  = (short*)(smem + 84480);     // ph2: [16][16][80], 40960 B

  const int tid = threadIdx.x;
  const int lane = tid & 63, w = tid >> 6;
  const int wm = w >> 3, wn = w & 7;
  const int quad = lane >> 4, l16 = lane & 15;
  const int m0 = blockIdx.x * 128;
  const int b = m0 >> 12;

  f32x4 acc[4][4] = {};

  // ================= phase 1: Q projection (BK=64, 8 steps) =================
  for (int k0 = 0; k0 < 512; k0 += 64) {
    // stage x -> xb bf16 [128][72]: 1024 thr x 8 elems, convert once
    {
      const int row = tid >> 3;
      const int kq = (tid & 7) * 8;
      const float* xp = x + (size_t)(m0 + row) * 512 + k0 + kq;
      float4v a0 = *(const float4v*)xp;
      float4v a1 = *(const float4v*)(xp + 4);
      uint4v u = {pkbf(a0[0], a0[1]), pkbf(a0[2], a0[3]),
                  pkbf(a1[0], a1[1]), pkbf(a1[2], a1[3])};
      *(bf16x8*)&xb[row * 72 + kq] = __builtin_bit_cast(bf16x8, u);
    }
    // stage wqt -> wsW [512][72]: 4 chunks of 128 rows
#pragma unroll
    for (int c = 0; c < 4; ++c) {
      const int row = c * 128 + (tid >> 3);
      const int col = (tid & 7) * 8;
      *(bf16x8*)&wsW[row * 72 + col] =
          *(const bf16x8*)(wqt + (size_t)row * 512 + k0 + col);
    }
    __syncthreads();

#pragma unroll
    for (int ks = 0; ks < 2; ++ks) {
      const int c0 = ks * 32 + quad * 8;
      bf16x8 af[4], bfr[4];
#pragma unroll
      for (int m = 0; m < 4; ++m)
        af[m] = *(bf16x8*)&xb[(wm * 64 + m * 16 + l16) * 72 + c0];
#pragma unroll
      for (int n = 0; n < 4; ++n)
        bfr[n] = *(bf16x8*)&wsW[(wn * 64 + n * 16 + l16) * 72 + c0];
#pragma unroll
      for (int m = 0; m < 4; ++m)
#pragma unroll
        for (int n = 0; n < 4; ++n)
          acc[m][n] = __builtin_amdgcn_mfma_f32_16x16x32_bf16(af[m], bfr[n],
                                                              acc[m][n], 0, 0, 0);
    }
    __syncthreads();
  }

  // ================= phase 2: 4 iters x 2 heads =================
#pragma unroll
  for (int it = 0; it < 4; ++it) {
    if (it) __syncthreads();

    // (a) Q dump: waves with wn in {2it, 2it+1} write slot wn&1 (their
    // phase-1 tile cols = head wn). Plain stride-72 writes, static acc idx.
    if ((wn >> 1) == it) {
      const int slot = wn & 1;
#pragma unroll
      for (int m = 0; m < 4; ++m)
#pragma unroll
        for (int n = 0; n < 4; ++n)
#pragma unroll
          for (int r = 0; r < 4; ++r)
            Qh[slot * 9216 + (wm * 64 + m * 16 + quad * 4 + r) * 72 +
               n * 16 + l16] = f2bf(acc[m][n][r]);
    }
    // (b) K stage x2 heads (rows 0..76; 77..79 garbage -> masked)
    for (int idx = tid; idx < 1232; idx += 1024) {
      const int sk = idx >= 616;
      const int e = idx - sk * 616;
      const int r = e >> 3, cc = (e & 7) * 8;
      *(bf16x8*)&Kl[sk * 5760 + r * 72 + cc] =
          *(const bf16x8*)(Kb + ((size_t)b * 77 + r) * 512 +
                           (it * 2 + sk) * 64 + cc);
    }
    // (c) V^T stage x2 heads, linear GLDS (12 chunks of 1 KB per head)
    for (int cid = w; cid < 24; cid += 16) {
      const int sv = cid >= 12;
      const int c12 = cid - sv * 12;
      GLDS16(Vtg + (size_t)(b * 8 + it * 2 + sv) * 6144 + c12 * 512 + lane * 8,
             Vt + sv * 6144 + c12 * 512);
    }
    __syncthreads();

    // (d) attention: head = it*2 + wm, q rows wn*16..+15
    bf16x8 qfr[2];
#pragma unroll
    for (int ks = 0; ks < 2; ++ks)
      qfr[ks] = *(bf16x8*)&Qh[wm * 9216 + (wn * 16 + l16) * 72 +
                              ks * 32 + quad * 8];

    f32x4 c[5] = {};
#pragma unroll
    for (int f = 0; f < 5; ++f)
#pragma unroll
      for (int ks = 0; ks < 2; ++ks) {
        bf16x8 a = *(bf16x8*)&Kl[wm * 5760 + (f * 16 + l16) * 72 +
                                 ks * 32 + quad * 8];
        c[f] = __builtin_amdgcn_mfma_f32_16x16x32_bf16(a, qfr[ks], c[f], 0, 0, 0);
      }

    float mx = -1e30f;
#pragma unroll
    for (int f = 0; f < 5; ++f)
#pragma unroll
      for (int r = 0; r < 4; ++r) {
        const int key = f * 16 + quad * 4 + r;
        float v = c[f][r] * 0.125f;
        v = (key < 77) ? v : -1e30f;
        c[f][r] = v;
        mx = fmaxf(mx, v);
      }
    mx = fmaxf(mx, __shfl_xor(mx, 16));
    mx = fmaxf(mx, __shfl_xor(mx, 32));

    short* pbase = Pw + (w * 16 + l16) * 80;
    float sum = 0.f;
#pragma unroll
    for (int f = 0; f < 5; ++f) {
      float e0 = __expf(c[f][0] - mx), e1 = __expf(c[f][1] - mx);
      float e2 = __expf(c[f][2] - mx), e3 = __expf(c[f][3] - mx);
      sum += (e0 + e1) + (e2 + e3);
      uint2v sv2 = {pkbf(e0, e1), pkbf(e2, e3)};
      *(uint2v*)(pbase + f * 16 + quad * 4) = sv2;
    }
    sum += __shfl_xor(sum, 16);
    sum += __shfl_xor(sum, 32);
    const float inv = 1.0f / sum;

    // P fragments: keys 0..63 from LDS; slab 2 (keys 64..95): 64..79 from
    // LDS for quad<2, keys 80..95 are zero IN-REGISTER (never stored).
    bf16x8 pb0 = *(bf16x8*)(pbase + quad * 8);
    bf16x8 pb1 = *(bf16x8*)(pbase + 32 + quad * 8);
    bf16x8 pb2 = bf16x8{0, 0, 0, 0, 0, 0, 0, 0};
    if (quad < 2) pb2 = *(bf16x8*)(pbase + 64 + quad * 8);

    f32x4 o[4] = {};
#pragma unroll
    for (int mt = 0; mt < 4; ++mt) {
      const short* vrow = &Vt[wm * 6144 + (mt * 16 + l16) * 96];
      o[mt] = __builtin_amdgcn_mfma_f32_16x16x32_bf16(
          *(bf16x8*)(vrow + quad * 8), pb0, o[mt], 0, 0, 0);
      o[mt] = __builtin_amdgcn_mfma_f32_16x16x32_bf16(
          *(bf16x8*)(vrow + 32 + quad * 8), pb1, o[mt], 0, 0, 0);
      o[mt] = __builtin_amdgcn_mfma_f32_16x16x32_bf16(
          *(bf16x8*)(vrow + 64 + quad * 8), pb2, o[mt], 0, 0, 0);
    }

    short* op = AOb + ((size_t)m0 + wn * 16 + l16) * 512 + (it * 2 + wm) * 64;
#pragma unroll
    for (int mt = 0; mt < 4; ++mt) {
      uint2v sv2 = {pkbf(o[mt][0] * inv, o[mt][1] * inv),
                    pkbf(o[mt][2] * inv, o[mt][3] * inv)};
      *(uint2v*)(op + mt * 16 + quad * 4) = sv2;
    }
  }
}

extern "C" void kernel_launch(void* const* d_in, const int* in_sizes, int n_in,
                              void* d_out, int out_size, void* d_ws, size_t ws_size,
                              hipStream_t stream) {
  const float* x   = (const float*)d_in[0];
  const float* ctx = (const float*)d_in[1];
  const float* Wq  = (const float*)d_in[2];
  const float* Wk  = (const float*)d_in[3];
  const float* Wv  = (const float*)d_in[4];
  const float* Wo  = (const float*)d_in[5];
  const float* bo  = (const float*)d_in[6];
  float* out = (float*)d_out;

  char* ws = (char*)d_ws;
  size_t off = 0;
  short* wqt = (short*)(ws + off); off += 512 * 512 * 2;
  short* wkt = (short*)(ws + off); off += 768 * 512 * 2;
  short* wvt = (short*)(ws + off); off += 768 * 512 * 2;
  short* wot = (short*)(ws + off); off += 512 * 512 * 2;
  short* Kb  = (short*)(ws + off); off += 1232 * 512 * 2;
  short* Vtg = (short*)(ws + off); off += (size_t)16 * 8 * 64 * 96 * 2;
  short* AOb = (short*)(ws + off); off += (size_t)65536 * 512 * 2;

  // weights -> bf16 transposed [N][K]
  wt_conv<<<dim3(8, 8), 256, 0, stream>>>(Wq, wqt, 512, 512);
  wt_conv<<<dim3(8, 12), 256, 0, stream>>>(Wk, wkt, 768, 512);
  wt_conv<<<dim3(8, 12), 256, 0, stream>>>(Wv, wvt, 768, 512);
  wt_conv<<<dim3(8, 8), 256, 0, stream>>>(Wo, wot, 512, 512);

  // zero-fill Vtg pads (16*8*64*96*2 B = 98304 float4), then K/V projections
  fill0<<<384, 256, 0, stream>>>((float4v*)Vtg, 98304);
  gemm_small<0><<<dim3(4, 39), 256, 0, stream>>>(ctx, wkt, Kb, 1232, 768);
  gemm_small<1><<<dim3(4, 39), 256, 0, stream>>>(ctx, wvt, Vtg, 1232, 768);

  // fused Q-proj + attention -> AOb bf16
  qattn<<<512, 1024, 0, stream>>>(x, wqt, Kb, Vtg, AOb);

  // output projection + bias -> f32 d_out
  gemm_m97<2><<<2048, 256, 0, stream>>>(AOb, wot, out, bo, 65536, 512, 512);
}

// Round 8
// 229.465 us; speedup vs baseline: 4.0986x; 1.0041x over previous
//
#include <hip/hip_runtime.h>
#include <hip/hip_bf16.h>
#include <stdint.h>

// CrossAttention: out = softmax((x@Wq)(ctx@Wk)^T * scale) @ (ctx@Wv) @ Wo + bo
// B=16, NQ=4096, NK=77, QD=512, CD=768, H=8, DH=64, INNER=512
//
// Round 8: SINGLE CHANGE vs round 7 — qattn gets __launch_bounds__(1024, 4).
// Round 7 compiled at 64 VGPR (default occupancy target for 1024-thr blocks)
// while acc[4][4] alone needs 64 -> hot-loop spills to scratch (L2-absorbed,
// invisible in FETCH/WRITE; visible as 67% idle). LDS already caps us at
// 1 block/CU = 4 waves/SIMD, so declaring (1024,4) unlocks 128 VGPR free.

typedef __attribute__((ext_vector_type(8))) short bf16x8;
typedef __attribute__((ext_vector_type(4))) float f32x4;
typedef __attribute__((ext_vector_type(4))) short short4v;
typedef __attribute__((ext_vector_type(4))) float float4v;
typedef __attribute__((ext_vector_type(2))) unsigned uint2v;
typedef __attribute__((ext_vector_type(4))) unsigned uint4v;

#define DEVINL __device__ __forceinline__

DEVINL short f2bf(float f) {
  unsigned u = __builtin_bit_cast(unsigned, f);
  unsigned r = (u + 0x7FFFu + ((u >> 16) & 1u)) >> 16;  // RNE
  return (short)(unsigned short)r;
}

// packed f32x2 -> bf16x2 (RTNE), single VALU op
DEVINL unsigned pkbf(float lo, float hi) {
  unsigned r;
  asm("v_cvt_pk_bf16_f32 %0, %1, %2" : "=v"(r) : "v"(lo), "v"(hi));
  return r;
}

#define GLDS16(gp, sp)                                                \
  __builtin_amdgcn_global_load_lds(                                   \
      (const __attribute__((address_space(1))) void*)(gp),            \
      (__attribute__((address_space(3))) void*)(sp), 16, 0, 0)

// ---------------- zero fill (float4 granules) ------------------------------
__global__ __launch_bounds__(256) void fill0(float4v* __restrict__ p, int n4) {
  int i = blockIdx.x * 256 + threadIdx.x;
  if (i < n4) p[i] = float4v{0.f, 0.f, 0.f, 0.f};
}

// ---------------- weight transpose+convert: W[K][N] f32 -> Wt[N][K] bf16 ----
__global__ __launch_bounds__(256) void wt_conv(const float* __restrict__ W,
                                               short* __restrict__ Wt,
                                               int K, int N) {
  __shared__ short Tl[64][65];
  const int kt = blockIdx.y * 64, nt = blockIdx.x * 64;
#pragma unroll
  for (int i = 0; i < 16; ++i) {
    int idx = threadIdx.x + i * 256;
    int r = idx >> 6, c = idx & 63;
    Tl[c][r] = f2bf(W[(size_t)(kt + r) * N + nt + c]);
  }
  __syncthreads();
#pragma unroll
  for (int i = 0; i < 16; ++i) {
    int idx = threadIdx.x + i * 256;
    int r = idx >> 6, c = idx & 63;
    Wt[(size_t)(nt + r) * K + kt + c] = Tl[r][c];
  }
}

// ---------------- m97-structure GEMM + XCD swizzle --------------------------
// C[M][N] = A[M][K] @ Bt[N][K]^T, bf16 in. 128x128 tile, BK=64, 4 waves.
// 1-D grid = (M/128)*(N/128), must be %8==0. OUT: 0=bf16, 2=f32+bias.
template <int OUT>
__global__ __launch_bounds__(256) void gemm_m97(const short* __restrict__ A,
                                                const short* __restrict__ Bt,
                                                void* __restrict__ Cv,
                                                const float* __restrict__ bias,
                                                int M, int N, int K) {
  __shared__ short Al[128 * 64];
  __shared__ short Bl[128 * 64];

  const int tid = threadIdx.x;
  const int lane = tid & 63, w = tid >> 6;
  const int wm = w >> 1, wn = w & 1;
  const int quad = lane >> 4, l16 = lane & 15;

  const int nwg = gridDim.x;
  const int cpx = nwg >> 3;
  const int wg = blockIdx.x;
  const int swz = (wg & 7) * cpx + (wg >> 3);
  const int nnt = N >> 7;
  const int m0 = (swz / nnt) * 128, n0 = (swz % nnt) * 128;

  const int lr = lane >> 3;
  const int lc = (lane & 7) * 8;

  f32x4 acc[4][4] = {};

  for (int k0 = 0; k0 < K; k0 += 64) {
#pragma unroll
    for (int p = 0; p < 4; ++p) {
      const int row = w * 32 + p * 8;
      GLDS16(A + (size_t)(m0 + row + lr) * K + k0 + lc, &Al[row * 64]);
      GLDS16(Bt + (size_t)(n0 + row + lr) * K + k0 + lc, &Bl[row * 64]);
    }
    __syncthreads();

#pragma unroll
    for (int ks = 0; ks < 2; ++ks) {
      bf16x8 af[4], bfr[4];
#pragma unroll
      for (int m = 0; m < 4; ++m)
        af[m] = *(bf16x8*)&Al[(wm * 64 + m * 16 + l16) * 64 + ks * 32 + quad * 8];
#pragma unroll
      for (int n = 0; n < 4; ++n)
        bfr[n] = *(bf16x8*)&Bl[(wn * 64 + n * 16 + l16) * 64 + ks * 32 + quad * 8];
#pragma unroll
      for (int m = 0; m < 4; ++m)
#pragma unroll
        for (int n = 0; n < 4; ++n)
          acc[m][n] = __builtin_amdgcn_mfma_f32_16x16x32_bf16(af[m], bfr[n],
                                                              acc[m][n], 0, 0, 0);
    }
    __syncthreads();
  }

#pragma unroll
  for (int m = 0; m < 4; ++m) {
#pragma unroll
    for (int n = 0; n < 4; ++n) {
      const int col = n0 + wn * 64 + n * 16 + l16;
      const int rowb = m0 + wm * 64 + m * 16 + quad * 4;
      const float badd = (OUT == 2) ? bias[col] : 0.0f;
#pragma unroll
      for (int r = 0; r < 4; ++r) {
        if constexpr (OUT == 0)
          ((short*)Cv)[(size_t)(rowb + r) * N + col] = f2bf(acc[m][n][r]);
        else
          ((float*)Cv)[(size_t)(rowb + r) * N + col] = acc[m][n][r] + badd;
      }
    }
  }
}

// ---------------- small GEMM (f32 A): C = A[M][K]f32 @ Bt[512][K]^T ---------
// TRANS=0: bf16 C[M][512].  TRANS=1: scatter to Vtg[((b*8+h)*64+d)*96+key].
template <int TRANS>
__global__ __launch_bounds__(256) void gemm_small(const float* __restrict__ A,
                                                  const short* __restrict__ Bt,
                                                  short* __restrict__ C,
                                                  int M, int K) {
  __shared__ short Al[32][40];
  __shared__ short Bl[128][40];

  const int tid = threadIdx.x;
  const int lane = tid & 63, wid = tid >> 6;
  const int wm = wid >> 1, wn = wid & 1;
  const int quad = lane >> 4, l16 = lane & 15;
  const int m0 = blockIdx.y * 32, n0 = blockIdx.x * 128;

  f32x4 acc[4] = {};

  for (int k0 = 0; k0 < K; k0 += 32) {
    for (int idx = tid; idx < 32 * 8; idx += 256) {
      int row = idx >> 3, kq = idx & 7;
      float4v v = {};
      if (m0 + row < M)
        v = *(const float4v*)(A + (size_t)(m0 + row) * K + k0 + kq * 4);
      short4v s = {f2bf(v[0]), f2bf(v[1]), f2bf(v[2]), f2bf(v[3])};
      *(short4v*)&Al[row][kq * 4] = s;
    }
    for (int idx = tid; idx < 512; idx += 256) {
      int row = idx >> 2, kq = idx & 3;
      *(bf16x8*)&Bl[row][kq * 8] =
          *(const bf16x8*)(Bt + (size_t)(n0 + row) * K + k0 + kq * 8);
    }
    __syncthreads();

    bf16x8 a = *(bf16x8*)&Al[wm * 16 + l16][quad * 8];
#pragma unroll
    for (int n = 0; n < 4; ++n) {
      bf16x8 b = *(bf16x8*)&Bl[wn * 64 + n * 16 + l16][quad * 8];
      acc[n] = __builtin_amdgcn_mfma_f32_16x16x32_bf16(a, b, acc[n], 0, 0, 0);
    }
    __syncthreads();
  }

#pragma unroll
  for (int n = 0; n < 4; ++n) {
    const int col = n0 + wn * 64 + n * 16 + l16;
    const int rowb = m0 + wm * 16 + quad * 4;
#pragma unroll
    for (int r = 0; r < 4; ++r) {
      const int rr = rowb + r;
      if (rr < M) {
        if constexpr (TRANS == 0) {
          C[(size_t)rr * 512 + col] = f2bf(acc[n][r]);
        } else {
          const int bb = rr / 77, key = rr - bb * 77;
          C[(size_t)((bb * 8 + (col >> 6)) * 64 + (col & 63)) * 96 + key] =
              f2bf(acc[n][r]);
        }
      }
    }
  }
}

// ---------------- fused Q-proj + attention ---------------------------------
// 1024 thr (16 waves). Phase 1: wave grid 2x8 (wm=w>>3 row-half, wn=w&7
// head/col), wave tile 64x64, acc[4][4]; xb/wsW reg-staged, padded stride 72.
// Phase 2: 4 iters x 2 heads; wave computes head it*2+wm for rows wn*16..+15.
// __launch_bounds__(1024, 4): LDS caps at 1 block/CU = 4 waves/SIMD anyway;
// declaring it unlocks the 128-VGPR budget (round 7 compiled at 64 -> spills).
__global__ __launch_bounds__(1024, 4) void qattn(const float* __restrict__ x,
                                                 const short* __restrict__ wqt,
                                                 const short* __restrict__ Kb,
                                                 const short* __restrict__ Vtg,
                                                 short* __restrict__ AOb) {
  __shared__ __align__(16) char smem[125440];
  short* xb  = (short*)smem;               // ph1: [128][72] bf16, 18432 B
  short* wsW = (short*)(smem + 18432);     // ph1: [512][72] bf16, 73728 B
  short* Qh  = (short*)smem;               // ph2: [2][128][72], 36864 B
  short* Kl  = (short*)(smem + 36864);     // ph2: [2][80][72], 23040 B
  short* Vt  = (short*)(smem + 59904);     // ph2: [2][64][96], 24576 B
  short* Pw  = (short*)(smem + 84480);     // ph2: [16][16][80], 40960 B

  const int tid = threadIdx.x;
  const int lane = tid & 63, w = tid >> 6;
  const int wm = w >> 3, wn = w & 7;
  const int quad = lane >> 4, l16 = lane & 15;
  const int m0 = blockIdx.x * 128;
  const int b = m0 >> 12;

  f32x4 acc[4][4] = {};

  // ================= phase 1: Q projection (BK=64, 8 steps) =================
  for (int k0 = 0; k0 < 512; k0 += 64) {
    // stage x -> xb bf16 [128][72]: 1024 thr x 8 elems, convert once
    {
      const int row = tid >> 3;
      const int kq = (tid & 7) * 8;
      const float* xp = x + (size_t)(m0 + row) * 512 + k0 + kq;
      float4v a0 = *(const float4v*)xp;
      float4v a1 = *(const float4v*)(xp + 4);
      uint4v u = {pkbf(a0[0], a0[1]), pkbf(a0[2], a0[3]),
                  pkbf(a1[0], a1[1]), pkbf(a1[2], a1[3])};
      *(bf16x8*)&xb[row * 72 + kq] = __builtin_bit_cast(bf16x8, u);
    }
    // stage wqt -> wsW [512][72]: 4 chunks of 128 rows
#pragma unroll
    for (int c = 0; c < 4; ++c) {
      const int row = c * 128 + (tid >> 3);
      const int col = (tid & 7) * 8;
      *(bf16x8*)&wsW[row * 72 + col] =
          *(const bf16x8*)(wqt + (size_t)row * 512 + k0 + col);
    }
    __syncthreads();

#pragma unroll
    for (int ks = 0; ks < 2; ++ks) {
      const int c0 = ks * 32 + quad * 8;
      bf16x8 af[4], bfr[4];
#pragma unroll
      for (int m = 0; m < 4; ++m)
        af[m] = *(bf16x8*)&xb[(wm * 64 + m * 16 + l16) * 72 + c0];
#pragma unroll
      for (int n = 0; n < 4; ++n)
        bfr[n] = *(bf16x8*)&wsW[(wn * 64 + n * 16 + l16) * 72 + c0];
#pragma unroll
      for (int m = 0; m < 4; ++m)
#pragma unroll
        for (int n = 0; n < 4; ++n)
          acc[m][n] = __builtin_amdgcn_mfma_f32_16x16x32_bf16(af[m], bfr[n],
                                                              acc[m][n], 0, 0, 0);
    }
    __syncthreads();
  }

  // ================= phase 2: 4 iters x 2 heads =================
#pragma unroll
  for (int it = 0; it < 4; ++it) {
    if (it) __syncthreads();

    // (a) Q dump: waves with wn in {2it, 2it+1} write slot wn&1 (their
    // phase-1 tile cols = head wn). Plain stride-72 writes, static acc idx.
    if ((wn >> 1) == it) {
      const int slot = wn & 1;
#pragma unroll
      for (int m = 0; m < 4; ++m)
#pragma unroll
        for (int n = 0; n < 4; ++n)
#pragma unroll
          for (int r = 0; r < 4; ++r)
            Qh[slot * 9216 + (wm * 64 + m * 16 + quad * 4 + r) * 72 +
               n * 16 + l16] = f2bf(acc[m][n][r]);
    }
    // (b) K stage x2 heads (rows 0..76; 77..79 garbage -> masked)
    for (int idx = tid; idx < 1232; idx += 1024) {
      const int sk = idx >= 616;
      const int e = idx - sk * 616;
      const int r = e >> 3, cc = (e & 7) * 8;
      *(bf16x8*)&Kl[sk * 5760 + r * 72 + cc] =
          *(const bf16x8*)(Kb + ((size_t)b * 77 + r) * 512 +
                           (it * 2 + sk) * 64 + cc);
    }
    // (c) V^T stage x2 heads, linear GLDS (12 chunks of 1 KB per head)
    for (int cid = w; cid < 24; cid += 16) {
      const int sv = cid >= 12;
      const int c12 = cid - sv * 12;
      GLDS16(Vtg + (size_t)(b * 8 + it * 2 + sv) * 6144 + c12 * 512 + lane * 8,
             Vt + sv * 6144 + c12 * 512);
    }
    __syncthreads();

    // (d) attention: head = it*2 + wm, q rows wn*16..+15
    bf16x8 qfr[2];
#pragma unroll
    for (int ks = 0; ks < 2; ++ks)
      qfr[ks] = *(bf16x8*)&Qh[wm * 9216 + (wn * 16 + l16) * 72 +
                              ks * 32 + quad * 8];

    f32x4 c[5] = {};
#pragma unroll
    for (int f = 0; f < 5; ++f)
#pragma unroll
      for (int ks = 0; ks < 2; ++ks) {
        bf16x8 a = *(bf16x8*)&Kl[wm * 5760 + (f * 16 + l16) * 72 +
                                 ks * 32 + quad * 8];
        c[f] = __builtin_amdgcn_mfma_f32_16x16x32_bf16(a, qfr[ks], c[f], 0, 0, 0);
      }

    float mx = -1e30f;
#pragma unroll
    for (int f = 0; f < 5; ++f)
#pragma unroll
      for (int r = 0; r < 4; ++r) {
        const int key = f * 16 + quad * 4 + r;
        float v = c[f][r] * 0.125f;
        v = (key < 77) ? v : -1e30f;
        c[f][r] = v;
        mx = fmaxf(mx, v);
      }
    mx = fmaxf(mx, __shfl_xor(mx, 16));
    mx = fmaxf(mx, __shfl_xor(mx, 32));

    short* pbase = Pw + (w * 16 + l16) * 80;
    float sum = 0.f;
#pragma unroll
    for (int f = 0; f < 5; ++f) {
      float e0 = __expf(c[f][0] - mx), e1 = __expf(c[f][1] - mx);
      float e2 = __expf(c[f][2] - mx), e3 = __expf(c[f][3] - mx);
      sum += (e0 + e1) + (e2 + e3);
      uint2v sv2 = {pkbf(e0, e1), pkbf(e2, e3)};
      *(uint2v*)(pbase + f * 16 + quad * 4) = sv2;
    }
    sum += __shfl_xor(sum, 16);
    sum += __shfl_xor(sum, 32);
    const float inv = 1.0f / sum;

    // P fragments: keys 0..63 from LDS; slab 2 (keys 64..95): 64..79 from
    // LDS for quad<2, keys 80..95 are zero IN-REGISTER (never stored).
    bf16x8 pb0 = *(bf16x8*)(pbase + quad * 8);
    bf16x8 pb1 = *(bf16x8*)(pbase + 32 + quad * 8);
    bf16x8 pb2 = bf16x8{0, 0, 0, 0, 0, 0, 0, 0};
    if (quad < 2) pb2 = *(bf16x8*)(pbase + 64 + quad * 8);

    f32x4 o[4] = {};
#pragma unroll
    for (int mt = 0; mt < 4; ++mt) {
      const short* vrow = &Vt[wm * 6144 + (mt * 16 + l16) * 96];
      o[mt] = __builtin_amdgcn_mfma_f32_16x16x32_bf16(
          *(bf16x8*)(vrow + quad * 8), pb0, o[mt], 0, 0, 0);
      o[mt] = __builtin_amdgcn_mfma_f32_16x16x32_bf16(
          *(bf16x8*)(vrow + 32 + quad * 8), pb1, o[mt], 0, 0, 0);
      o[mt] = __builtin_amdgcn_mfma_f32_16x16x32_bf16(
          *(bf16x8*)(vrow + 64 + quad * 8), pb2, o[mt], 0, 0, 0);
    }

    short* op = AOb + ((size_t)m0 + wn * 16 + l16) * 512 + (it * 2 + wm) * 64;
#pragma unroll
    for (int mt = 0; mt < 4; ++mt) {
      uint2v sv2 = {pkbf(o[mt][0] * inv, o[mt][1] * inv),
                    pkbf(o[mt][2] * inv, o[mt][3] * inv)};
      *(uint2v*)(op + mt * 16 + quad * 4) = sv2;
    }
  }
}

extern "C" void kernel_launch(void* const* d_in, const int* in_sizes, int n_in,
                              void* d_out, int out_size, void* d_ws, size_t ws_size,
                              hipStream_t stream) {
  const float* x   = (const float*)d_in[0];
  const float* ctx = (const float*)d_in[1];
  const float* Wq  = (const float*)d_in[2];
  const float* Wk  = (const float*)d_in[3];
  const float* Wv  = (const float*)d_in[4];
  const float* Wo  = (const float*)d_in[5];
  const float* bo  = (const float*)d_in[6];
  float* out = (float*)d_out;

  char* ws = (char*)d_ws;
  size_t off = 0;
  short* wqt = (short*)(ws + off); off += 512 * 512 * 2;
  short* wkt = (short*)(ws + off); off += 768 * 512 * 2;
  short* wvt = (short*)(ws + off); off += 768 * 512 * 2;
  short* wot = (short*)(ws + off); off += 512 * 512 * 2;
  short* Kb  = (short*)(ws + off); off += 1232 * 512 * 2;
  short* Vtg = (short*)(ws + off); off += (size_t)16 * 8 * 64 * 96 * 2;
  short* AOb = (short*)(ws + off); off += (size_t)65536 * 512 * 2;

  // weights -> bf16 transposed [N][K]
  wt_conv<<<dim3(8, 8), 256, 0, stream>>>(Wq, wqt, 512, 512);
  wt_conv<<<dim3(8, 12), 256, 0, stream>>>(Wk, wkt, 768, 512);
  wt_conv<<<dim3(8, 12), 256, 0, stream>>>(Wv, wvt, 768, 512);
  wt_conv<<<dim3(8, 8), 256, 0, stream>>>(Wo, wot, 512, 512);

  // zero-fill Vtg pads (16*8*64*96*2 B = 98304 float4), then K/V projections
  fill0<<<384, 256, 0, stream>>>((float4v*)Vtg, 98304);
  gemm_small<0><<<dim3(4, 39), 256, 0, stream>>>(ctx, wkt, Kb, 1232, 768);
  gemm_small<1><<<dim3(4, 39), 256, 0, stream>>>(ctx, wvt, Vtg, 1232, 768);

  // fused Q-proj + attention -> AOb bf16
  qattn<<<512, 1024, 0, stream>>>(x, wqt, Kb, Vtg, AOb);

  // output projection + bias -> f32 d_out
  gemm_m97<2><<<2048, 256, 0, stream>>>(AOb, wot, out, bo, 65536, 512, 512);
}

// Round 9
// 226.510 us; speedup vs baseline: 4.1521x; 1.0130x over previous
//
#include <hip/hip_runtime.h>
#include <hip/hip_bf16.h>
#include <stdint.h>

// CrossAttention: out = softmax((x@Wq)(ctx@Wk)^T * scale) @ (ctx@Wv) @ Wo + bo
// B=16, NQ=4096, NK=77, QD=512, CD=768, H=8, DH=64, INNER=512
//
// Round 9: qattn phase-1 restructured as BK=32 double-buffered reg-staged
// pipeline, ONE __syncthreads per K-step, prefetch issued AFTER the barrier
// (its vmcnt-wait lands at the ds_write use next step, after a full compute
// phase of overlap -> no barrier ever drains an in-flight prefetch).
// Phase 2 and all other kernels byte-identical to round 8.

typedef __attribute__((ext_vector_type(8))) short bf16x8;
typedef __attribute__((ext_vector_type(4))) float f32x4;
typedef __attribute__((ext_vector_type(4))) short short4v;
typedef __attribute__((ext_vector_type(4))) float float4v;
typedef __attribute__((ext_vector_type(2))) unsigned uint2v;
typedef __attribute__((ext_vector_type(4))) unsigned uint4v;

#define DEVINL __device__ __forceinline__

DEVINL short f2bf(float f) {
  unsigned u = __builtin_bit_cast(unsigned, f);
  unsigned r = (u + 0x7FFFu + ((u >> 16) & 1u)) >> 16;  // RNE
  return (short)(unsigned short)r;
}

// packed f32x2 -> bf16x2 (RTNE), single VALU op
DEVINL unsigned pkbf(float lo, float hi) {
  unsigned r;
  asm("v_cvt_pk_bf16_f32 %0, %1, %2" : "=v"(r) : "v"(lo), "v"(hi));
  return r;
}

#define GLDS16(gp, sp)                                                \
  __builtin_amdgcn_global_load_lds(                                   \
      (const __attribute__((address_space(1))) void*)(gp),            \
      (__attribute__((address_space(3))) void*)(sp), 16, 0, 0)

// ---------------- zero fill (float4 granules) ------------------------------
__global__ __launch_bounds__(256) void fill0(float4v* __restrict__ p, int n4) {
  int i = blockIdx.x * 256 + threadIdx.x;
  if (i < n4) p[i] = float4v{0.f, 0.f, 0.f, 0.f};
}

// ---------------- weight transpose+convert: W[K][N] f32 -> Wt[N][K] bf16 ----
__global__ __launch_bounds__(256) void wt_conv(const float* __restrict__ W,
                                               short* __restrict__ Wt,
                                               int K, int N) {
  __shared__ short Tl[64][65];
  const int kt = blockIdx.y * 64, nt = blockIdx.x * 64;
#pragma unroll
  for (int i = 0; i < 16; ++i) {
    int idx = threadIdx.x + i * 256;
    int r = idx >> 6, c = idx & 63;
    Tl[c][r] = f2bf(W[(size_t)(kt + r) * N + nt + c]);
  }
  __syncthreads();
#pragma unroll
  for (int i = 0; i < 16; ++i) {
    int idx = threadIdx.x + i * 256;
    int r = idx >> 6, c = idx & 63;
    Wt[(size_t)(nt + r) * K + kt + c] = Tl[r][c];
  }
}

// ---------------- m97-structure GEMM + XCD swizzle --------------------------
// C[M][N] = A[M][K] @ Bt[N][K]^T, bf16 in. 128x128 tile, BK=64, 4 waves.
// 1-D grid = (M/128)*(N/128), must be %8==0. OUT: 0=bf16, 2=f32+bias.
template <int OUT>
__global__ __launch_bounds__(256) void gemm_m97(const short* __restrict__ A,
                                                const short* __restrict__ Bt,
                                                void* __restrict__ Cv,
                                                const float* __restrict__ bias,
                                                int M, int N, int K) {
  __shared__ short Al[128 * 64];
  __shared__ short Bl[128 * 64];

  const int tid = threadIdx.x;
  const int lane = tid & 63, w = tid >> 6;
  const int wm = w >> 1, wn = w & 1;
  const int quad = lane >> 4, l16 = lane & 15;

  const int nwg = gridDim.x;
  const int cpx = nwg >> 3;
  const int wg = blockIdx.x;
  const int swz = (wg & 7) * cpx + (wg >> 3);
  const int nnt = N >> 7;
  const int m0 = (swz / nnt) * 128, n0 = (swz % nnt) * 128;

  const int lr = lane >> 3;
  const int lc = (lane & 7) * 8;

  f32x4 acc[4][4] = {};

  for (int k0 = 0; k0 < K; k0 += 64) {
#pragma unroll
    for (int p = 0; p < 4; ++p) {
      const int row = w * 32 + p * 8;
      GLDS16(A + (size_t)(m0 + row + lr) * K + k0 + lc, &Al[row * 64]);
      GLDS16(Bt + (size_t)(n0 + row + lr) * K + k0 + lc, &Bl[row * 64]);
    }
    __syncthreads();

#pragma unroll
    for (int ks = 0; ks < 2; ++ks) {
      bf16x8 af[4], bfr[4];
#pragma unroll
      for (int m = 0; m < 4; ++m)
        af[m] = *(bf16x8*)&Al[(wm * 64 + m * 16 + l16) * 64 + ks * 32 + quad * 8];
#pragma unroll
      for (int n = 0; n < 4; ++n)
        bfr[n] = *(bf16x8*)&Bl[(wn * 64 + n * 16 + l16) * 64 + ks * 32 + quad * 8];
#pragma unroll
      for (int m = 0; m < 4; ++m)
#pragma unroll
        for (int n = 0; n < 4; ++n)
          acc[m][n] = __builtin_amdgcn_mfma_f32_16x16x32_bf16(af[m], bfr[n],
                                                              acc[m][n], 0, 0, 0);
    }
    __syncthreads();
  }

#pragma unroll
  for (int m = 0; m < 4; ++m) {
#pragma unroll
    for (int n = 0; n < 4; ++n) {
      const int col = n0 + wn * 64 + n * 16 + l16;
      const int rowb = m0 + wm * 64 + m * 16 + quad * 4;
      const float badd = (OUT == 2) ? bias[col] : 0.0f;
#pragma unroll
      for (int r = 0; r < 4; ++r) {
        if constexpr (OUT == 0)
          ((short*)Cv)[(size_t)(rowb + r) * N + col] = f2bf(acc[m][n][r]);
        else
          ((float*)Cv)[(size_t)(rowb + r) * N + col] = acc[m][n][r] + badd;
      }
    }
  }
}

// ---------------- small GEMM (f32 A): C = A[M][K]f32 @ Bt[512][K]^T ---------
// TRANS=0: bf16 C[M][512].  TRANS=1: scatter to Vtg[((b*8+h)*64+d)*96+key].
template <int TRANS>
__global__ __launch_bounds__(256) void gemm_small(const float* __restrict__ A,
                                                  const short* __restrict__ Bt,
                                                  short* __restrict__ C,
                                                  int M, int K) {
  __shared__ short Al[32][40];
  __shared__ short Bl[128][40];

  const int tid = threadIdx.x;
  const int lane = tid & 63, wid = tid >> 6;
  const int wm = wid >> 1, wn = wid & 1;
  const int quad = lane >> 4, l16 = lane & 15;
  const int m0 = blockIdx.y * 32, n0 = blockIdx.x * 128;

  f32x4 acc[4] = {};

  for (int k0 = 0; k0 < K; k0 += 32) {
    for (int idx = tid; idx < 32 * 8; idx += 256) {
      int row = idx >> 3, kq = idx & 7;
      float4v v = {};
      if (m0 + row < M)
        v = *(const float4v*)(A + (size_t)(m0 + row) * K + k0 + kq * 4);
      short4v s = {f2bf(v[0]), f2bf(v[1]), f2bf(v[2]), f2bf(v[3])};
      *(short4v*)&Al[row][kq * 4] = s;
    }
    for (int idx = tid; idx < 512; idx += 256) {
      int row = idx >> 2, kq = idx & 3;
      *(bf16x8*)&Bl[row][kq * 8] =
          *(const bf16x8*)(Bt + (size_t)(n0 + row) * K + k0 + kq * 8);
    }
    __syncthreads();

    bf16x8 a = *(bf16x8*)&Al[wm * 16 + l16][quad * 8];
#pragma unroll
    for (int n = 0; n < 4; ++n) {
      bf16x8 b = *(bf16x8*)&Bl[wn * 64 + n * 16 + l16][quad * 8];
      acc[n] = __builtin_amdgcn_mfma_f32_16x16x32_bf16(a, b, acc[n], 0, 0, 0);
    }
    __syncthreads();
  }

#pragma unroll
  for (int n = 0; n < 4; ++n) {
    const int col = n0 + wn * 64 + n * 16 + l16;
    const int rowb = m0 + wm * 16 + quad * 4;
#pragma unroll
    for (int r = 0; r < 4; ++r) {
      const int rr = rowb + r;
      if (rr < M) {
        if constexpr (TRANS == 0) {
          C[(size_t)rr * 512 + col] = f2bf(acc[n][r]);
        } else {
          const int bb = rr / 77, key = rr - bb * 77;
          C[(size_t)((bb * 8 + (col >> 6)) * 64 + (col & 63)) * 96 + key] =
              f2bf(acc[n][r]);
        }
      }
    }
  }
}

// ---------------- fused Q-proj + attention ---------------------------------
// 1024 thr (16 waves). Phase 1: BK=32, 16 steps, LDS double-buffer
// (xb[2][128][40], wsW[2][512][40]), reg-staged, prefetch after barrier,
// ONE __syncthreads per step. Phase 2: identical to rounds 7/8.
__global__ __launch_bounds__(1024, 4) void qattn(const float* __restrict__ x,
                                                 const short* __restrict__ wqt,
                                                 const short* __restrict__ Kb,
                                                 const short* __restrict__ Vtg,
                                                 short* __restrict__ AOb) {
  __shared__ __align__(16) char smem[125440];
  short* xb  = (short*)smem;               // ph1: [2][128][40] bf16, 20480 B
  short* wsW = (short*)(smem + 20480);     // ph1: [2][512][40] bf16, 81920 B
  short* Qh  = (short*)smem;               // ph2: [2][128][72], 36864 B
  short* Kl  = (short*)(smem + 36864);     // ph2: [2][80][72], 23040 B
  short* Vt  = (short*)(smem + 59904);     // ph2: [2][64][96], 24576 B
  short* Pw  = (short*)(smem + 84480);     // ph2: [16][16][80], 40960 B

  const int tid = threadIdx.x;
  const int lane = tid & 63, w = tid >> 6;
  const int wm = w >> 3, wn = w & 7;
  const int quad = lane >> 4, l16 = lane & 15;
  const int m0 = blockIdx.x * 128;
  const int b = m0 >> 12;

  f32x4 acc[4][4] = {};

  // ============ phase 1: Q projection, BK=32 pipelined (16 steps) ==========
  // staging ownership: x: row=tid>>3, 4 floats at col (tid&7)*4
  //                    wqt: chunks c=tid and c=tid+1024; row=c>>2, 8 shorts
  const int xrow = tid >> 3, xcol = (tid & 7) * 4;
  const int wr0 = tid >> 2, wc0 = (tid & 3) * 8;            // chunk c=tid
  const int wr1 = (tid + 1024) >> 2, wc1 = wc0;             // chunk c=tid+1024

  const float* xg = x + (size_t)(m0 + xrow) * 512 + xcol;
  const short* wg0 = wqt + (size_t)wr0 * 512 + wc0;
  const short* wg1 = wqt + (size_t)wr1 * 512 + wc1;

  float4v px;
  bf16x8 pw0, pw1;
  // prologue: load step 0
  px = *(const float4v*)(xg);
  pw0 = *(const bf16x8*)(wg0);
  pw1 = *(const bf16x8*)(wg1);

  for (int t = 0; t < 16; ++t) {
    short* xbuf = xb + (t & 1) * 5120;     // 128*40
    short* wbuf = wsW + (t & 1) * 20480;   // 512*40

    // write staged regs -> LDS (auto vmcnt-wait on px/pw here)
    *(uint2v*)&xbuf[xrow * 40 + xcol] =
        uint2v{pkbf(px[0], px[1]), pkbf(px[2], px[3])};
    *(bf16x8*)&wbuf[wr0 * 40 + wc0] = pw0;
    *(bf16x8*)&wbuf[wr1 * 40 + wc1] = pw1;

    __syncthreads();  // drains ds_writes; no reg-loads outstanding

    // prefetch step t+1 (drained only at its use next iteration)
    if (t < 15) {
      const int k1 = (t + 1) * 32;
      px = *(const float4v*)(xg + k1);
      pw0 = *(const bf16x8*)(wg0 + k1);
      pw1 = *(const bf16x8*)(wg1 + k1);
    }

    // compute from buf[t&1] (overlaps the prefetch loads)
    bf16x8 af[4], bfr[4];
#pragma unroll
    for (int m = 0; m < 4; ++m)
      af[m] = *(bf16x8*)&xbuf[(wm * 64 + m * 16 + l16) * 40 + quad * 8];
#pragma unroll
    for (int n = 0; n < 4; ++n)
      bfr[n] = *(bf16x8*)&wbuf[(wn * 64 + n * 16 + l16) * 40 + quad * 8];
#pragma unroll
    for (int m = 0; m < 4; ++m)
#pragma unroll
      for (int n = 0; n < 4; ++n)
        acc[m][n] = __builtin_amdgcn_mfma_f32_16x16x32_bf16(af[m], bfr[n],
                                                            acc[m][n], 0, 0, 0);
  }
  __syncthreads();  // phase-1 LDS reads done before phase-2 overlay writes

  // ================= phase 2: 4 iters x 2 heads (unchanged) ================
#pragma unroll
  for (int it = 0; it < 4; ++it) {
    if (it) __syncthreads();

    // (a) Q dump: waves with wn in {2it, 2it+1} write slot wn&1
    if ((wn >> 1) == it) {
      const int slot = wn & 1;
#pragma unroll
      for (int m = 0; m < 4; ++m)
#pragma unroll
        for (int n = 0; n < 4; ++n)
#pragma unroll
          for (int r = 0; r < 4; ++r)
            Qh[slot * 9216 + (wm * 64 + m * 16 + quad * 4 + r) * 72 +
               n * 16 + l16] = f2bf(acc[m][n][r]);
    }
    // (b) K stage x2 heads (rows 0..76; 77..79 garbage -> masked)
    for (int idx = tid; idx < 1232; idx += 1024) {
      const int sk = idx >= 616;
      const int e = idx - sk * 616;
      const int r = e >> 3, cc = (e & 7) * 8;
      *(bf16x8*)&Kl[sk * 5760 + r * 72 + cc] =
          *(const bf16x8*)(Kb + ((size_t)b * 77 + r) * 512 +
                           (it * 2 + sk) * 64 + cc);
    }
    // (c) V^T stage x2 heads, linear GLDS (12 chunks of 1 KB per head)
    for (int cid = w; cid < 24; cid += 16) {
      const int sv = cid >= 12;
      const int c12 = cid - sv * 12;
      GLDS16(Vtg + (size_t)(b * 8 + it * 2 + sv) * 6144 + c12 * 512 + lane * 8,
             Vt + sv * 6144 + c12 * 512);
    }
    __syncthreads();

    // (d) attention: head = it*2 + wm, q rows wn*16..+15
    bf16x8 qfr[2];
#pragma unroll
    for (int ks = 0; ks < 2; ++ks)
      qfr[ks] = *(bf16x8*)&Qh[wm * 9216 + (wn * 16 + l16) * 72 +
                              ks * 32 + quad * 8];

    f32x4 c[5] = {};
#pragma unroll
    for (int f = 0; f < 5; ++f)
#pragma unroll
      for (int ks = 0; ks < 2; ++ks) {
        bf16x8 a = *(bf16x8*)&Kl[wm * 5760 + (f * 16 + l16) * 72 +
                                 ks * 32 + quad * 8];
        c[f] = __builtin_amdgcn_mfma_f32_16x16x32_bf16(a, qfr[ks], c[f], 0, 0, 0);
      }

    float mx = -1e30f;
#pragma unroll
    for (int f = 0; f < 5; ++f)
#pragma unroll
      for (int r = 0; r < 4; ++r) {
        const int key = f * 16 + quad * 4 + r;
        float v = c[f][r] * 0.125f;
        v = (key < 77) ? v : -1e30f;
        c[f][r] = v;
        mx = fmaxf(mx, v);
      }
    mx = fmaxf(mx, __shfl_xor(mx, 16));
    mx = fmaxf(mx, __shfl_xor(mx, 32));

    short* pbase = Pw + (w * 16 + l16) * 80;
    float sum = 0.f;
#pragma unroll
    for (int f = 0; f < 5; ++f) {
      float e0 = __expf(c[f][0] - mx), e1 = __expf(c[f][1] - mx);
      float e2 = __expf(c[f][2] - mx), e3 = __expf(c[f][3] - mx);
      sum += (e0 + e1) + (e2 + e3);
      uint2v sv2 = {pkbf(e0, e1), pkbf(e2, e3)};
      *(uint2v*)(pbase + f * 16 + quad * 4) = sv2;
    }
    sum += __shfl_xor(sum, 16);
    sum += __shfl_xor(sum, 32);
    const float inv = 1.0f / sum;

    // P fragments: keys 0..63 from LDS; keys 64..79 for quad<2, 80..95 zero.
    bf16x8 pb0 = *(bf16x8*)(pbase + quad * 8);
    bf16x8 pb1 = *(bf16x8*)(pbase + 32 + quad * 8);
    bf16x8 pb2 = bf16x8{0, 0, 0, 0, 0, 0, 0, 0};
    if (quad < 2) pb2 = *(bf16x8*)(pbase + 64 + quad * 8);

    f32x4 o[4] = {};
#pragma unroll
    for (int mt = 0; mt < 4; ++mt) {
      const short* vrow = &Vt[wm * 6144 + (mt * 16 + l16) * 96];
      o[mt] = __builtin_amdgcn_mfma_f32_16x16x32_bf16(
          *(bf16x8*)(vrow + quad * 8), pb0, o[mt], 0, 0, 0);
      o[mt] = __builtin_amdgcn_mfma_f32_16x16x32_bf16(
          *(bf16x8*)(vrow + 32 + quad * 8), pb1, o[mt], 0, 0, 0);
      o[mt] = __builtin_amdgcn_mfma_f32_16x16x32_bf16(
          *(bf16x8*)(vrow + 64 + quad * 8), pb2, o[mt], 0, 0, 0);
    }

    short* op = AOb + ((size_t)m0 + wn * 16 + l16) * 512 + (it * 2 + wm) * 64;
#pragma unroll
    for (int mt = 0; mt < 4; ++mt) {
      uint2v sv2 = {pkbf(o[mt][0] * inv, o[mt][1] * inv),
                    pkbf(o[mt][2] * inv, o[mt][3] * inv)};
      *(uint2v*)(op + mt * 16 + quad * 4) = sv2;
    }
  }
}

extern "C" void kernel_launch(void* const* d_in, const int* in_sizes, int n_in,
                              void* d_out, int out_size, void* d_ws, size_t ws_size,
                              hipStream_t stream) {
  const float* x   = (const float*)d_in[0];
  const float* ctx = (const float*)d_in[1];
  const float* Wq  = (const float*)d_in[2];
  const float* Wk  = (const float*)d_in[3];
  const float* Wv  = (const float*)d_in[4];
  const float* Wo  = (const float*)d_in[5];
  const float* bo  = (const float*)d_in[6];
  float* out = (float*)d_out;

  char* ws = (char*)d_ws;
  size_t off = 0;
  short* wqt = (short*)(ws + off); off += 512 * 512 * 2;
  short* wkt = (short*)(ws + off); off += 768 * 512 * 2;
  short* wvt = (short*)(ws + off); off += 768 * 512 * 2;
  short* wot = (short*)(ws + off); off += 512 * 512 * 2;
  short* Kb  = (short*)(ws + off); off += 1232 * 512 * 2;
  short* Vtg = (short*)(ws + off); off += (size_t)16 * 8 * 64 * 96 * 2;
  short* AOb = (short*)(ws + off); off += (size_t)65536 * 512 * 2;

  // weights -> bf16 transposed [N][K]
  wt_conv<<<dim3(8, 8), 256, 0, stream>>>(Wq, wqt, 512, 512);
  wt_conv<<<dim3(8, 12), 256, 0, stream>>>(Wk, wkt, 768, 512);
  wt_conv<<<dim3(8, 12), 256, 0, stream>>>(Wv, wvt, 768, 512);
  wt_conv<<<dim3(8, 8), 256, 0, stream>>>(Wo, wot, 512, 512);

  // zero-fill Vtg pads, then K/V projections from f32 ctx
  fill0<<<384, 256, 0, stream>>>((float4v*)Vtg, 98304);
  gemm_small<0><<<dim3(4, 39), 256, 0, stream>>>(ctx, wkt, Kb, 1232, 768);
  gemm_small<1><<<dim3(4, 39), 256, 0, stream>>>(ctx, wvt, Vtg, 1232, 768);

  // fused Q-proj + attention -> AOb bf16
  qattn<<<512, 1024, 0, stream>>>(x, wqt, Kb, Vtg, AOb);

  // output projection + bias -> f32 d_out
  gemm_m97<2><<<2048, 256, 0, stream>>>(AOb, wot, out, bo, 65536, 512, 512);
}